// Round 9
// baseline (1067.638 us; speedup 1.0000x reference)
//
#include <hip/hip_runtime.h>
#include <hip/hip_fp16.h>

#define B_    64
#define V1_   4096
#define V2_   1024
#define DF_   8
#define K_    25
#define NP_   13      /* u32 pair-planes per column: pairs (k0,k1)..(k24,-) */
#define F1_   32
#define F2_   64
#define FC1F_ 512
#define FC2F_ 10
#define E1_   65536
#define E2_   16384
#define C1_   512
#define C2_   2048
#define FCIN_ 16384
#define NPAIR1_ (C1_/4)   /* 128 pairs, 4 cols each */

typedef short bf16x8 __attribute__((ext_vector_type(8)));
typedef float f32x4  __attribute__((ext_vector_type(4)));

// acc += f16(hi16 of q) * f16(lo16 of g)   [f32 accumulate]
#define FMA_MIX_LO(acc, qv, gv) \
    asm("v_fma_mix_f32 %0, %1, %2, %0 op_sel:[1,0,0] op_sel_hi:[1,1,0]" \
        : "+v"(acc) : "v"(qv), "v"(gv))
// acc += f16(hi16 of q) * f16(hi16 of g)
#define FMA_MIX_HI(acc, qv, gv) \
    asm("v_fma_mix_f32 %0, %1, %2, %0 op_sel:[1,1,0] op_sel_hi:[1,1,0]" \
        : "+v"(acc) : "v"(qv), "v"(gv))

__device__ __forceinline__ unsigned short f2bf(float x) {
    unsigned u = __float_as_uint(x);
    u += 0x7FFFu + ((u >> 16) & 1u);
    return (unsigned short)(u >> 16);
}
__device__ __forceinline__ float h2f_lo(unsigned u) {
    return __half2float(__ushort_as_half((unsigned short)(u & 0xFFFFu)));
}
__device__ __forceinline__ float h2f_hi(unsigned u) {
    return __half2float(__ushort_as_half((unsigned short)(u >> 16)));
}

// ---------- input transpose: x[b,v,fin] -> X0T[(fin*64+b)][v] ----------
__global__ __launch_bounds__(256) void k_transpose_x(const float* __restrict__ x,
                                                     float* __restrict__ X0T) {
    __shared__ float tsh[DF_][B_][16];
    const int t = threadIdx.x;
    const int v0 = blockIdx.x * 16;
    for (int rep = 0; rep < 4; ++rep) {
        int idx = rep*256 + t;
        int b = idx >> 4, vv = idx & 15;
        const float4* p = (const float4*)&x[((size_t)b*V1_ + v0 + vv)*DF_];
        float4 a0 = p[0], a1 = p[1];
        tsh[0][b][vv]=a0.x; tsh[1][b][vv]=a0.y; tsh[2][b][vv]=a0.z; tsh[3][b][vv]=a0.w;
        tsh[4][b][vv]=a1.x; tsh[5][b][vv]=a1.y; tsh[6][b][vv]=a1.z; tsh[7][b][vv]=a1.w;
    }
    __syncthreads();
    for (int rep = 0; rep < 32; ++rep) {
        int idx = rep*256 + t;
        int vv = idx & 15, b = (idx >> 4) & 63, fin = idx >> 10;
        X0T[(size_t)(fin*64 + b)*V1_ + v0 + vv] = tsh[fin][b][vv];
    }
}

// ---------- CSR build (padded to 4-edge alignment, packed 4B edges) ----------
__global__ __launch_bounds__(256) void k_count(const int* __restrict__ rows, int E,
                                               int* __restrict__ cnt) {
    int e = blockIdx.x*256 + threadIdx.x;
    if (e < E) atomicAdd(&cnt[rows[e]], 1);
}

__global__ __launch_bounds__(256) void k_scan(const int* __restrict__ cnt, int V,
                                              int* __restrict__ offs, int* __restrict__ cursor) {
    __shared__ int psum[256];
    int t = threadIdx.x;
    int chunk = V >> 8;
    int lo = t*chunk;
    int s = 0;
    for (int i = lo; i < lo+chunk; ++i) s += (cnt[i] + 3) & ~3;
    psum[t] = s;
    __syncthreads();
    for (int off = 1; off < 256; off <<= 1) {
        int val = (t >= off) ? psum[t-off] : 0;
        __syncthreads();
        psum[t] += val;
        __syncthreads();
    }
    int run = (t == 0) ? 0 : psum[t-1];
    for (int i = lo; i < lo+chunk; ++i) {
        offs[i] = run; cursor[i] = run;
        run += (cnt[i] + 3) & ~3;
    }
    if (t == 255) offs[V] = run;
}

// edge payload: {f16 weight hi16, (col<<shift) lo16}
__global__ __launch_bounds__(256) void k_scatter(const int* __restrict__ rows,
                                                 const int* __restrict__ cols,
                                                 const float* __restrict__ vals, int E,
                                                 int shift,
                                                 int* __restrict__ cursor,
                                                 unsigned* __restrict__ ep) {
    int e = blockIdx.x*256 + threadIdx.x;
    if (e < E) {
        int p = atomicAdd(&cursor[rows[e]], 1);
        unsigned hv = (unsigned)__half_as_ushort(__float2half(vals[e]));
        ep[p] = (hv << 16) | ((unsigned)cols[e] << shift);
    }
}

// ---------- layer-1 Chebyshev: paired blocks, 4 cols/pair, vertex-split halves ----------
// block = (pair p, half h). Full V f16x4 state in LDS; each block computes rows of its
// half, halves exchanged via global double-buffer + device-scope flag handshake.
// stack: u32 pair-planes  stk[(c*13 + plane)*V + v]
template<int V, int THREADS>
__global__ __launch_bounds__(THREADS, 4) void k_cheb1(
        const float* __restrict__ X0T,
        const int* __restrict__ offs,
        const unsigned* __restrict__ ep,
        unsigned* __restrict__ stk,
        uint2* __restrict__ xchg,
        int* __restrict__ flags) {
    constexpr int HV  = V/2;
    constexpr int RPT = HV / THREADS;      // 2
    __shared__ uint2 buf[2*V];
    const int p = blockIdx.x >> 1, h = blockIdx.x & 1;
    const int c0 = p*4;
    const int row0 = h*HV;
    const int t = threadIdx.x;
    int e0r[RPT], e1r[RPT];
    unsigned tlo[RPT][4];
    unsigned* __restrict__ pl[4];
#pragma unroll
    for (int j = 0; j < 4; ++j) pl[j] = stk + (size_t)(c0+j)*NP_*V;

    // k = 0: load FULL x0 (all V rows, 4 cols) into buf[0..V)
    for (int i = 0; i < V/THREADS; ++i) {
        const int v = i*THREADS + t;
        float xj[4];
#pragma unroll
        for (int j = 0; j < 4; ++j) xj[j] = X0T[(size_t)(c0+j)*V + v];
        __half2 ha = __floats2half2_rn(xj[0], xj[1]);
        __half2 hb = __floats2half2_rn(xj[2], xj[3]);
        buf[v] = make_uint2(*(const unsigned*)&ha, *(const unsigned*)&hb);
    }
#pragma unroll
    for (int r = 0; r < RPT; ++r) {            // own-half row metadata + x0 stash
        const int v = row0 + r*THREADS + t;
        e0r[r] = offs[v]; e1r[r] = offs[v+1];
#pragma unroll
        for (int j = 0; j < 4; ++j) tlo[r][j] = f2bf(X0T[(size_t)(c0+j)*V + v]);
    }
    __syncthreads();

    for (int k = 1; k <= 24; ++k) {
        const bool first = (k == 1), last = (k == 24);
        const int plane = (k & 1) ? (k >> 1) : -1;
        const uint2* __restrict__ src = buf + ((k & 1) ? 0 : V);
        uint2*       __restrict__ dst = buf + ((k & 1) ? V : 0);
        const int xbase = (((k & 1)*NPAIR1_ + p)*2 + h)*HV;

#pragma unroll
        for (int r = 0; r < RPT; ++r) {
            const int v = row0 + r*THREADS + t;
            float acc[4][4];
#pragma unroll
            for (int j = 0; j < 4; ++j)
#pragma unroll
                for (int i = 0; i < 4; ++i) acc[j][i] = 0.f;
            const int ee0 = e0r[r], ee1 = e1r[r];
            uint4 q = *(const uint4*)&ep[ee0];
            for (int e = ee0; e < ee1; e += 4) {
                const uint4 qn = *(const uint4*)&ep[e + 4];
                const uint2 g0 = *(const uint2*)((const char*)src + (q.x & 0xFFFFu));
                const uint2 g1 = *(const uint2*)((const char*)src + (q.y & 0xFFFFu));
                const uint2 g2 = *(const uint2*)((const char*)src + (q.z & 0xFFFFu));
                const uint2 g3 = *(const uint2*)((const char*)src + (q.w & 0xFFFFu));
                FMA_MIX_LO(acc[0][0], q.x, g0.x); FMA_MIX_HI(acc[1][0], q.x, g0.x);
                FMA_MIX_LO(acc[2][0], q.x, g0.y); FMA_MIX_HI(acc[3][0], q.x, g0.y);
                FMA_MIX_LO(acc[0][1], q.y, g1.x); FMA_MIX_HI(acc[1][1], q.y, g1.x);
                FMA_MIX_LO(acc[2][1], q.y, g1.y); FMA_MIX_HI(acc[3][1], q.y, g1.y);
                FMA_MIX_LO(acc[0][2], q.z, g2.x); FMA_MIX_HI(acc[1][2], q.z, g2.x);
                FMA_MIX_LO(acc[2][2], q.z, g2.y); FMA_MIX_HI(acc[3][2], q.z, g2.y);
                FMA_MIX_LO(acc[0][3], q.w, g3.x); FMA_MIX_HI(acc[1][3], q.w, g3.x);
                FMA_MIX_LO(acc[2][3], q.w, g3.y); FMA_MIX_HI(acc[3][3], q.w, g3.y);
                q = qn;
            }
            float gs[4], xn[4];
#pragma unroll
            for (int j = 0; j < 4; ++j)
                gs[j] = (acc[j][0]+acc[j][1])+(acc[j][2]+acc[j][3]);
            if (first) {
#pragma unroll
                for (int j = 0; j < 4; ++j) xn[j] = gs[j];
            } else {
                const uint2 old = dst[v];        // own row's x_{k-2}
                xn[0] = fmaf(2.f, gs[0], -h2f_lo(old.x));
                xn[1] = fmaf(2.f, gs[1], -h2f_hi(old.x));
                xn[2] = fmaf(2.f, gs[2], -h2f_lo(old.y));
                xn[3] = fmaf(2.f, gs[3], -h2f_hi(old.y));
            }
            __half2 ha = __floats2half2_rn(xn[0], xn[1]);
            __half2 hb = __floats2half2_rn(xn[2], xn[3]);
            const uint2 pk = make_uint2(*(const unsigned*)&ha, *(const unsigned*)&hb);
            if (!last) {
                dst[v] = pk;
                xchg[xbase + (v - row0)] = pk;   // publish own half
            }
            unsigned hh[4];
#pragma unroll
            for (int j = 0; j < 4; ++j) hh[j] = f2bf(xn[j]);
            if (plane < 0) {
#pragma unroll
                for (int j = 0; j < 4; ++j) tlo[r][j] = hh[j];
            } else {
#pragma unroll
                for (int j = 0; j < 4; ++j)
                    pl[j][(size_t)plane*V + v] = tlo[r][j] | (hh[j] << 16);
            }
        }
        if (!last) {
            __syncthreads();                      // all xchg stores issued
            if (t == 0) {
                __threadfence();
                __hip_atomic_store(&flags[p*2 + h], k, __ATOMIC_RELEASE,
                                   __HIP_MEMORY_SCOPE_AGENT);
                while (__hip_atomic_load(&flags[p*2 + (1-h)], __ATOMIC_ACQUIRE,
                                         __HIP_MEMORY_SCOPE_AGENT) < k) {}
                __threadfence();
            }
            __syncthreads();                      // peer data visible
            const int pbase = (((k & 1)*NPAIR1_ + p)*2 + (1-h))*HV;
            const int prow0 = (1-h)*HV;
#pragma unroll
            for (int r = 0; r < RPT; ++r) {
                const int vv = r*THREADS + t;
                dst[prow0 + vv] = xchg[pbase + vv];
            }
        }
        __syncthreads();
    }

#pragma unroll
    for (int r = 0; r < RPT; ++r) {               // plane 12 = {bf16(x24), 0}
        const int v = row0 + r*THREADS + t;
#pragma unroll
        for (int j = 0; j < 4; ++j)
            pl[j][(size_t)12*V + v] = tlo[r][j];
    }
}

// ---------- layer-2 Chebyshev: 4 cols/block, f16x4 LDS ping-pong, asm fma_mix ----------
template<int V, int THREADS, int MINW>
__global__ __launch_bounds__(THREADS, MINW) void k_cheb2(
        const float* __restrict__ X0T,
        const int* __restrict__ offs,
        const unsigned* __restrict__ ep,
        unsigned* __restrict__ stk) {
    constexpr int RPT = V / THREADS;     // 2
    __shared__ uint2 buf[2*V];
    const int c0 = blockIdx.x*4;
    const int t = threadIdx.x;
    int e0r[RPT], e1r[RPT];
    unsigned tlo[RPT][4];
    unsigned* __restrict__ pl[4];
#pragma unroll
    for (int j = 0; j < 4; ++j) pl[j] = stk + (size_t)(c0+j)*NP_*V;

#pragma unroll
    for (int r = 0; r < RPT; ++r) {
        const int v = r*THREADS + t;
        e0r[r] = offs[v]; e1r[r] = offs[v+1];
        float xj[4];
#pragma unroll
        for (int j = 0; j < 4; ++j) {
            xj[j] = X0T[(size_t)(c0+j)*V + v];
            tlo[r][j] = f2bf(xj[j]);
        }
        __half2 ha = __floats2half2_rn(xj[0], xj[1]);
        __half2 hb = __floats2half2_rn(xj[2], xj[3]);
        buf[v] = make_uint2(*(const unsigned*)&ha, *(const unsigned*)&hb);
    }
    __syncthreads();

    auto step = [&](const uint2* __restrict__ src, uint2* __restrict__ dst,
                    bool first, bool last, int plane) {
#pragma unroll
        for (int r = 0; r < RPT; ++r) {
            const int v = r*THREADS + t;
            float acc[4][4];
#pragma unroll
            for (int j = 0; j < 4; ++j)
#pragma unroll
                for (int i = 0; i < 4; ++i) acc[j][i] = 0.f;
            const int ee0 = e0r[r], ee1 = e1r[r];
            uint4 q = *(const uint4*)&ep[ee0];
            for (int e = ee0; e < ee1; e += 4) {
                const uint4 qn = *(const uint4*)&ep[e + 4];
                const uint2 g0 = *(const uint2*)((const char*)src + (q.x & 0xFFFFu));
                const uint2 g1 = *(const uint2*)((const char*)src + (q.y & 0xFFFFu));
                const uint2 g2 = *(const uint2*)((const char*)src + (q.z & 0xFFFFu));
                const uint2 g3 = *(const uint2*)((const char*)src + (q.w & 0xFFFFu));
                FMA_MIX_LO(acc[0][0], q.x, g0.x); FMA_MIX_HI(acc[1][0], q.x, g0.x);
                FMA_MIX_LO(acc[2][0], q.x, g0.y); FMA_MIX_HI(acc[3][0], q.x, g0.y);
                FMA_MIX_LO(acc[0][1], q.y, g1.x); FMA_MIX_HI(acc[1][1], q.y, g1.x);
                FMA_MIX_LO(acc[2][1], q.y, g1.y); FMA_MIX_HI(acc[3][1], q.y, g1.y);
                FMA_MIX_LO(acc[0][2], q.z, g2.x); FMA_MIX_HI(acc[1][2], q.z, g2.x);
                FMA_MIX_LO(acc[2][2], q.z, g2.y); FMA_MIX_HI(acc[3][2], q.z, g2.y);
                FMA_MIX_LO(acc[0][3], q.w, g3.x); FMA_MIX_HI(acc[1][3], q.w, g3.x);
                FMA_MIX_LO(acc[2][3], q.w, g3.y); FMA_MIX_HI(acc[3][3], q.w, g3.y);
                q = qn;
            }
            float gs[4];
#pragma unroll
            for (int j = 0; j < 4; ++j)
                gs[j] = (acc[j][0]+acc[j][1])+(acc[j][2]+acc[j][3]);
            float xn[4];
            if (first) {
#pragma unroll
                for (int j = 0; j < 4; ++j) xn[j] = gs[j];
            } else {
                const uint2 old = dst[v];
                xn[0] = fmaf(2.f, gs[0], -h2f_lo(old.x));
                xn[1] = fmaf(2.f, gs[1], -h2f_hi(old.x));
                xn[2] = fmaf(2.f, gs[2], -h2f_lo(old.y));
                xn[3] = fmaf(2.f, gs[3], -h2f_hi(old.y));
            }
            if (!last) {
                __half2 ha = __floats2half2_rn(xn[0], xn[1]);
                __half2 hb = __floats2half2_rn(xn[2], xn[3]);
                dst[v] = make_uint2(*(const unsigned*)&ha, *(const unsigned*)&hb);
            }
            unsigned h[4];
#pragma unroll
            for (int j = 0; j < 4; ++j) h[j] = f2bf(xn[j]);
            if (plane < 0) {
#pragma unroll
                for (int j = 0; j < 4; ++j) tlo[r][j] = h[j];
            } else {
#pragma unroll
                for (int j = 0; j < 4; ++j)
                    pl[j][(size_t)plane*V + v] = tlo[r][j] | (h[j] << 16);
            }
        }
        __syncthreads();
    };

    step(buf, buf + V, true, false, 0);
    for (int k = 2; k < 24; k += 2) {
        step(buf + V, buf, false, false, -1);
        step(buf, buf + V, false, false, (k + 1) >> 1);
    }
    step(buf + V, buf, false, true, -1);

#pragma unroll
    for (int r = 0; r < RPT; ++r) {
        const int v = r*THREADS + t;
#pragma unroll
        for (int j = 0; j < 4; ++j)
            pl[j][(size_t)12*V + v] = tlo[r][j];
    }
}

// ---------- W prep: Wb[fin][g][f][kk] = bf16(W[f][fin*25 + g*8+kk]), 0-padded ----------
template<int FIN, int F>
__global__ __launch_bounds__(256) void k_wprep(const float* __restrict__ W,
                                               unsigned short* __restrict__ Wb) {
    int idx = blockIdx.x*256 + threadIdx.x;
    int kk  = idx & 7;
    int f   = (idx >> 3) % F;
    int g   = (idx >> 3) / F % 4;
    int fin = idx / (8*F*4);
    int k = g*8 + kk;
    Wb[idx] = (k < K_) ? f2bf(W[(size_t)f*(FIN*K_) + fin*K_ + k]) : 0;
}

// ---------- layer-1 MFMA GEMM + relu + pool -> X0T2[(f*64+b)][v2] ----------
__global__ __launch_bounds__(256) void k_gemm1(const unsigned* __restrict__ STK,
                                               const unsigned short* __restrict__ Wb,
                                               const float* __restrict__ bias,
                                               float* __restrict__ X0T2) {
    __shared__ float Tsm[32][36];
    const int t = threadIdx.x, lane = t & 63, wave = t >> 6;
    const int b = blockIdx.x;
    const int v0 = blockIdx.y*128 + wave*32;
    const int m = lane & 15, g = lane >> 4;
    int offp[4];
#pragma unroll
    for (int p = 0; p < 4; ++p) {
        int pl = 4*g + p; if (pl > 12) pl = 12;   // clamp: k>=26 lands on pair12, Wb=0 kills it
        offp[p] = pl*V1_ + v0 + m;
    }

    f32x4 acc[2][2];
#pragma unroll
    for (int mt = 0; mt < 2; ++mt)
#pragma unroll
        for (int ft = 0; ft < 2; ++ft) acc[mt][ft] = (f32x4){0.f,0.f,0.f,0.f};

#pragma unroll
    for (int fin = 0; fin < DF_; ++fin) {
        const unsigned* sp = STK + (size_t)(fin*64 + b)*(NP_*V1_);
        unsigned ua[4], ub[4];
#pragma unroll
        for (int p = 0; p < 4; ++p) { ua[p] = sp[offp[p]]; ub[p] = sp[offp[p] + 16]; }
        bf16x8 a0, a1;
        __builtin_memcpy(&a0, ua, 16);
        __builtin_memcpy(&a1, ub, 16);
        const bf16x8 w0 = *(const bf16x8*)&Wb[((fin*4+g)*F1_ + m)*8];
        const bf16x8 w1 = *(const bf16x8*)&Wb[((fin*4+g)*F1_ + 16 + m)*8];
        acc[0][0] = __builtin_amdgcn_mfma_f32_16x16x32_bf16(a0, w0, acc[0][0], 0,0,0);
        acc[0][1] = __builtin_amdgcn_mfma_f32_16x16x32_bf16(a0, w1, acc[0][1], 0,0,0);
        acc[1][0] = __builtin_amdgcn_mfma_f32_16x16x32_bf16(a1, w0, acc[1][0], 0,0,0);
        acc[1][1] = __builtin_amdgcn_mfma_f32_16x16x32_bf16(a1, w1, acc[1][1], 0,0,0);
    }
    float bv[2] = { bias[m], bias[16+m] };
#pragma unroll
    for (int mt = 0; mt < 2; ++mt)
#pragma unroll
        for (int ft = 0; ft < 2; ++ft) {
            f32x4 a = acc[mt][ft];
            float mx = fmaxf(fmaxf(a[0],a[1]), fmaxf(a[2],a[3])) + bv[ft];
            Tsm[ft*16 + m][wave*8 + mt*4 + g] = fmaxf(mx, 0.f);
        }
    __syncthreads();
    const int f = t >> 3, vg = t & 7;
    float4 o = *(const float4*)&Tsm[f][vg*4];
    *(float4*)&X0T2[(size_t)(f*64+b)*V2_ + blockIdx.y*32 + vg*4] = o;
}

// ---------- layer-2 MFMA GEMM + relu + pool -> FCINT[v2*64+f][b] ----------
__global__ __launch_bounds__(256) void k_gemm2(const unsigned* __restrict__ STK,
                                               const unsigned short* __restrict__ Wb,
                                               const float* __restrict__ bias,
                                               float* __restrict__ FCINT) {
    const int t = threadIdx.x, lane = t & 63, wave = t >> 6;
    const int b = blockIdx.x;
    const int v0 = blockIdx.y*128 + wave*32;
    const int m = lane & 15, g = lane >> 4;
    int offp[4];
#pragma unroll
    for (int p = 0; p < 4; ++p) {
        int pl = 4*g + p; if (pl > 12) pl = 12;
        offp[p] = pl*V2_ + v0 + m;
    }

    f32x4 acc[2][4];
#pragma unroll
    for (int mt = 0; mt < 2; ++mt)
#pragma unroll
        for (int ft = 0; ft < 4; ++ft) acc[mt][ft] = (f32x4){0.f,0.f,0.f,0.f};

#pragma unroll 4
    for (int fin = 0; fin < F1_; ++fin) {
        const unsigned* sp = STK + (size_t)(fin*64 + b)*(NP_*V2_);
        unsigned ua[4], ub[4];
#pragma unroll
        for (int p = 0; p < 4; ++p) { ua[p] = sp[offp[p]]; ub[p] = sp[offp[p] + 16]; }
        bf16x8 a0, a1;
        __builtin_memcpy(&a0, ua, 16);
        __builtin_memcpy(&a1, ub, 16);
#pragma unroll
        for (int ft = 0; ft < 4; ++ft) {
            const bf16x8 bw = *(const bf16x8*)&Wb[((fin*4+g)*F2_ + ft*16 + m)*8];
            acc[0][ft] = __builtin_amdgcn_mfma_f32_16x16x32_bf16(a0, bw, acc[0][ft], 0,0,0);
            acc[1][ft] = __builtin_amdgcn_mfma_f32_16x16x32_bf16(a1, bw, acc[1][ft], 0,0,0);
        }
    }
#pragma unroll
    for (int mt = 0; mt < 2; ++mt)
#pragma unroll
        for (int ft = 0; ft < 4; ++ft) {
            f32x4 a = acc[mt][ft];
            float mx = fmaxf(fmaxf(a[0],a[1]), fmaxf(a[2],a[3])) + bias[ft*16 + m];
            mx = fmaxf(mx, 0.f);
            int v2 = blockIdx.y*32 + wave*8 + mt*4 + g;
            FCINT[((size_t)v2*64 + ft*16 + m)*64 + b] = mx;
        }
}

// ---------- FC1: O[b][j] (+= atomics over i-splits), AT layout [i][b] ----------
__global__ __launch_bounds__(256) void k_fc1_init(const float* __restrict__ bias,
                                                  float* __restrict__ O) {
    int idx = blockIdx.x*256 + threadIdx.x;
    O[idx] = bias[idx & (FC1F_-1)];
}

__global__ __launch_bounds__(256) void k_fc1(const float* __restrict__ AT,
                                             const float* __restrict__ W,
                                             float* __restrict__ O) {
    const int t = threadIdx.x;
    const int b = t & 63;
    const int jq = __builtin_amdgcn_readfirstlane(t >> 6);
    const int j0 = blockIdx.x*32 + jq*8;
    const int i0 = blockIdx.y*1024;
    float acc[8] = {};
    for (int i = i0; i < i0 + 1024; i += 4) {
        float a0 = AT[(size_t)(i+0)*64 + b];
        float a1 = AT[(size_t)(i+1)*64 + b];
        float a2 = AT[(size_t)(i+2)*64 + b];
        float a3 = AT[(size_t)(i+3)*64 + b];
#pragma unroll
        for (int jj = 0; jj < 8; ++jj) {
            const float* wp = &W[(size_t)(j0+jj)*FCIN_ + i];
            acc[jj] = fmaf(a0, wp[0], acc[jj]);
            acc[jj] = fmaf(a1, wp[1], acc[jj]);
            acc[jj] = fmaf(a2, wp[2], acc[jj]);
            acc[jj] = fmaf(a3, wp[3], acc[jj]);
        }
    }
#pragma unroll
    for (int jj = 0; jj < 8; ++jj)
        atomicAdd(&O[b*FC1F_ + j0 + jj], acc[jj]);
}

// ---------- FC2 (relu on FC1 output applied here) ----------
__global__ void k_fc2(const float* __restrict__ O1, const float* __restrict__ W2,
                      const float* __restrict__ b2, float* __restrict__ out) {
    int c = blockIdx.x;
    int b = threadIdx.x;
    float s = b2[c];
    for (int j = 0; j < FC1F_; ++j)
        s = fmaf(fmaxf(O1[b*FC1F_ + j], 0.f), W2[c*FC1F_ + j], s);
    out[b*FC2F_ + c] = s;
}

extern "C" void kernel_launch(void* const* d_in, const int* in_sizes, int n_in,
                              void* d_out, int out_size, void* d_ws, size_t ws_size,
                              hipStream_t stream) {
    const float* x   = (const float*)d_in[0];
    const int*   l1r = (const int*)d_in[1];
    const int*   l1c = (const int*)d_in[2];
    const float* l1v = (const float*)d_in[3];
    const int*   l2r = (const int*)d_in[4];
    const int*   l2c = (const int*)d_in[5];
    const float* l2v = (const float*)d_in[6];
    const float* w1  = (const float*)d_in[7];
    const float* b1  = (const float*)d_in[8];
    const float* w2  = (const float*)d_in[9];
    const float* b2  = (const float*)d_in[10];
    const float* fw1 = (const float*)d_in[11];
    const float* fb1 = (const float*)d_in[12];
    const float* fw2 = (const float*)d_in[13];
    const float* fb2 = (const float*)d_in[14];
    float* out = (float*)d_out;

    char* wsp = (char*)d_ws;
    size_t off = 0;
    auto alloc = [&](size_t bytes) -> void* {
        void* p = wsp + off;
        off += (bytes + 255) & ~size_t(255);
        return p;
    };
    float*    X0T1  = (float*)alloc((size_t)C1_*V1_*4);
    unsigned* STACK = (unsigned*)alloc((size_t)C1_*NP_*V1_*4);   // == C2_*NP_*V2_*4, reused
    float*    X0T2  = (float*)alloc((size_t)C2_*V2_*4);
    float*    FCINT = (float*)alloc((size_t)FCIN_*B_*4);
    float*    FC1O  = (float*)alloc((size_t)B_*FC1F_*4);
    unsigned short* WB1 = (unsigned short*)alloc((size_t)DF_*4*F1_*8*2);
    unsigned short* WB2 = (unsigned short*)alloc((size_t)F1_*4*F2_*8*2);
    uint2*    XCHG  = (uint2*)alloc((size_t)2*NPAIR1_*2*(V1_/2)*8);
    int*      FLAGS = (int*)alloc((size_t)NPAIR1_*2*4);
    int*      cnt1  = (int*)alloc(V1_*4);
    int*      offs1 = (int*)alloc((V1_+1)*4);
    int*      cur1  = (int*)alloc(V1_*4);
    unsigned* ep1   = (unsigned*)alloc((size_t)(E1_ + 4*V1_ + 8)*4);
    int*      cnt2  = (int*)alloc(V2_*4);
    int*      offs2 = (int*)alloc((V2_+1)*4);
    int*      cur2  = (int*)alloc(V2_*4);
    unsigned* ep2   = (unsigned*)alloc((size_t)(E2_ + 4*V2_ + 8)*4);

    // --- CSR build both layers + W prep ---
    hipMemsetAsync(cnt1, 0, V1_*4, stream);
    hipMemsetAsync(ep1, 0, (size_t)(E1_ + 4*V1_ + 8)*4, stream);
    hipMemsetAsync(cnt2, 0, V2_*4, stream);
    hipMemsetAsync(ep2, 0, (size_t)(E2_ + 4*V2_ + 8)*4, stream);
    hipMemsetAsync(FLAGS, 0, (size_t)NPAIR1_*2*4, stream);
    hipLaunchKernelGGL(k_count,   dim3(E1_/256), dim3(256), 0, stream, l1r, E1_, cnt1);
    hipLaunchKernelGGL(k_scan,    dim3(1),       dim3(256), 0, stream, cnt1, V1_, offs1, cur1);
    hipLaunchKernelGGL(k_scatter, dim3(E1_/256), dim3(256), 0, stream, l1r, l1c, l1v, E1_, 3, cur1, ep1);
    hipLaunchKernelGGL(k_count,   dim3(E2_/256), dim3(256), 0, stream, l2r, E2_, cnt2);
    hipLaunchKernelGGL(k_scan,    dim3(1),       dim3(256), 0, stream, cnt2, V2_, offs2, cur2);
    hipLaunchKernelGGL(k_scatter, dim3(E2_/256), dim3(256), 0, stream, l2r, l2c, l2v, E2_, 3, cur2, ep2);
    hipLaunchKernelGGL((k_wprep<DF_,F1_>), dim3(DF_*4*F1_*8/256), dim3(256), 0, stream, w1, WB1);
    hipLaunchKernelGGL((k_wprep<F1_,F2_>), dim3(F1_*4*F2_*8/256), dim3(256), 0, stream, w2, WB2);

    // --- layer 1 ---
    hipLaunchKernelGGL(k_transpose_x, dim3(V1_/16), dim3(256), 0, stream, x, X0T1);
    hipLaunchKernelGGL((k_cheb1<V1_,1024>), dim3(NPAIR1_*2), dim3(1024), 0, stream,
                       X0T1, offs1, ep1, STACK, XCHG, FLAGS);
    hipLaunchKernelGGL(k_gemm1, dim3(64, 32), dim3(256), 0, stream, STACK, WB1, b1, X0T2);

    // --- layer 2 ---
    hipLaunchKernelGGL((k_cheb2<V2_,512,4>), dim3(C2_/4), dim3(512), 0, stream,
                       X0T2, offs2, ep2, STACK);
    hipLaunchKernelGGL(k_gemm2, dim3(64, 8), dim3(256), 0, stream, STACK, WB2, b2, FCINT);

    // --- FC ---
    hipLaunchKernelGGL(k_fc1_init, dim3(B_*FC1F_/256), dim3(256), 0, stream, fb1, FC1O);
    hipLaunchKernelGGL(k_fc1, dim3(16, 16), dim3(256), 0, stream, FCINT, fw1, FC1O);
    hipLaunchKernelGGL(k_fc2, dim3(FC2F_), dim3(B_), 0, stream, FC1O, fw2, fb2, out);
}

// Round 10
// 681.535 us; speedup vs baseline: 1.5665x; 1.5665x over previous
//
#include <hip/hip_runtime.h>
#include <hip/hip_fp16.h>

#define B_    64
#define V1_   4096
#define V2_   1024
#define DF_   8
#define K_    25
#define NP_   13      /* u32 pair-planes per column: pairs (k0,k1)..(k24,-) */
#define F1_   32
#define F2_   64
#define FC1F_ 512
#define FC2F_ 10
#define E1_   65536
#define E2_   16384
#define C1_   512
#define C2_   2048
#define FCIN_ 16384
#define ZC1_  (E1_ + 4*V1_)   /* known-zero packet index in ep1 */
#define ZC2_  (E2_ + 4*V2_)   /* known-zero packet index in ep2 */

typedef short bf16x8 __attribute__((ext_vector_type(8)));
typedef float f32x4  __attribute__((ext_vector_type(4)));

// acc += f16(hi16 of q) * f16(lo16 of g)   [f32 accumulate]
#define FMA_MIX_LO(acc, qv, gv) \
    asm("v_fma_mix_f32 %0, %1, %2, %0 op_sel:[1,0,0] op_sel_hi:[1,1,0]" \
        : "+v"(acc) : "v"(qv), "v"(gv))
// acc += f16(hi16 of q) * f16(hi16 of g)
#define FMA_MIX_HI(acc, qv, gv) \
    asm("v_fma_mix_f32 %0, %1, %2, %0 op_sel:[1,1,0] op_sel_hi:[1,1,0]" \
        : "+v"(acc) : "v"(qv), "v"(gv))

__device__ __forceinline__ unsigned short f2bf(float x) {
    unsigned u = __float_as_uint(x);
    u += 0x7FFFu + ((u >> 16) & 1u);
    return (unsigned short)(u >> 16);
}
__device__ __forceinline__ float h2f_lo(unsigned u) {
    return __half2float(__ushort_as_half((unsigned short)(u & 0xFFFFu)));
}
__device__ __forceinline__ float h2f_hi(unsigned u) {
    return __half2float(__ushort_as_half((unsigned short)(u >> 16)));
}

// ---------- input transpose: x[b,v,fin] -> X0T[(fin*64+b)][v] ----------
__global__ __launch_bounds__(256) void k_transpose_x(const float* __restrict__ x,
                                                     float* __restrict__ X0T) {
    __shared__ float tsh[DF_][B_][16];
    const int t = threadIdx.x;
    const int v0 = blockIdx.x * 16;
    for (int rep = 0; rep < 4; ++rep) {
        int idx = rep*256 + t;
        int b = idx >> 4, vv = idx & 15;
        const float4* p = (const float4*)&x[((size_t)b*V1_ + v0 + vv)*DF_];
        float4 a0 = p[0], a1 = p[1];
        tsh[0][b][vv]=a0.x; tsh[1][b][vv]=a0.y; tsh[2][b][vv]=a0.z; tsh[3][b][vv]=a0.w;
        tsh[4][b][vv]=a1.x; tsh[5][b][vv]=a1.y; tsh[6][b][vv]=a1.z; tsh[7][b][vv]=a1.w;
    }
    __syncthreads();
    for (int rep = 0; rep < 32; ++rep) {
        int idx = rep*256 + t;
        int vv = idx & 15, b = (idx >> 4) & 63, fin = idx >> 10;
        X0T[(size_t)(fin*64 + b)*V1_ + v0 + vv] = tsh[fin][b][vv];
    }
}

// ---------- CSR build (padded to 4-edge alignment, packed 4B edges) ----------
__global__ __launch_bounds__(256) void k_count(const int* __restrict__ rows, int E,
                                               int* __restrict__ cnt) {
    int e = blockIdx.x*256 + threadIdx.x;
    if (e < E) atomicAdd(&cnt[rows[e]], 1);
}

__global__ __launch_bounds__(256) void k_scan(const int* __restrict__ cnt, int V,
                                              int* __restrict__ offs, int* __restrict__ cursor) {
    __shared__ int psum[256];
    int t = threadIdx.x;
    int chunk = V >> 8;
    int lo = t*chunk;
    int s = 0;
    for (int i = lo; i < lo+chunk; ++i) s += (cnt[i] + 3) & ~3;
    psum[t] = s;
    __syncthreads();
    for (int off = 1; off < 256; off <<= 1) {
        int val = (t >= off) ? psum[t-off] : 0;
        __syncthreads();
        psum[t] += val;
        __syncthreads();
    }
    int run = (t == 0) ? 0 : psum[t-1];
    for (int i = lo; i < lo+chunk; ++i) {
        offs[i] = run; cursor[i] = run;
        run += (cnt[i] + 3) & ~3;
    }
    if (t == 255) offs[V] = run;
}

// edge payload: {f16 weight hi16, (col<<shift) lo16}
__global__ __launch_bounds__(256) void k_scatter(const int* __restrict__ rows,
                                                 const int* __restrict__ cols,
                                                 const float* __restrict__ vals, int E,
                                                 int shift,
                                                 int* __restrict__ cursor,
                                                 unsigned* __restrict__ ep) {
    int e = blockIdx.x*256 + threadIdx.x;
    if (e < E) {
        int p = atomicAdd(&cursor[rows[e]], 1);
        unsigned hv = (unsigned)__half_as_ushort(__float2half(vals[e]));
        ep[p] = (hv << 16) | ((unsigned)cols[e] << shift);
    }
}

// ---------- layer-1 Chebyshev: 2 cols/block, f16x2 LDS ping-pong ----------
// interleaved-row edge loop: packet i of all RPT rows per iteration, prefetch i+1.
// stack: u32 pair-planes  stk[(c*13 + plane)*V + v]
template<int V, int THREADS, int MINW>
__global__ __launch_bounds__(THREADS, MINW) void k_cheb1(
        const float* __restrict__ X0T,
        const int* __restrict__ offs,
        const unsigned* __restrict__ ep,
        unsigned* __restrict__ stk) {
    constexpr int RPT = V / THREADS;       // 4
    __shared__ unsigned buf[2*V];
    const int c0 = blockIdx.x*2;
    const int t = threadIdx.x;
    int e0r[RPT], e1r[RPT];
    unsigned tlo0[RPT], tlo1[RPT];
    unsigned* __restrict__ p0 = stk + (size_t)(c0+0)*NP_*V;
    unsigned* __restrict__ p1 = stk + (size_t)(c0+1)*NP_*V;

#pragma unroll
    for (int r = 0; r < RPT; ++r) {
        const int v = r*THREADS + t;
        e0r[r] = offs[v]; e1r[r] = offs[v+1];
        const float x0 = X0T[(size_t)c0*V + v];
        const float x1 = X0T[(size_t)(c0+1)*V + v];
        __half2 hh = __floats2half2_rn(x0, x1);
        buf[v] = *(const unsigned*)&hh;
        tlo0[r] = f2bf(x0); tlo1[r] = f2bf(x1);
    }
    __syncthreads();

    auto step = [&](const unsigned* __restrict__ src, unsigned* __restrict__ dst,
                    bool first, bool last, int plane) {
        float a0[RPT], a1[RPT], b0[RPT], b1[RPT];
        uint4 q[RPT], qn[RPT];
        int mxp = 0;
#pragma unroll
        for (int r = 0; r < RPT; ++r) {
            a0[r]=0.f; a1[r]=0.f; b0[r]=0.f; b1[r]=0.f;
            const int np = (e1r[r] - e0r[r]) >> 2;
            mxp = np > mxp ? np : mxp;
            q[r] = *(const uint4*)&ep[(e0r[r] < e1r[r]) ? e0r[r] : ZC1_];
        }
        for (int i = 0; i < mxp; ++i) {
#pragma unroll
            for (int r = 0; r < RPT; ++r) {
                const int e = e0r[r] + (i+1)*4;
                qn[r] = *(const uint4*)&ep[(e < e1r[r]) ? e : ZC1_];
            }
#pragma unroll
            for (int r = 0; r < RPT; ++r) {
                const unsigned g0 = *(const unsigned*)((const char*)src + (q[r].x & 0xFFFFu));
                const unsigned g1 = *(const unsigned*)((const char*)src + (q[r].y & 0xFFFFu));
                const unsigned g2 = *(const unsigned*)((const char*)src + (q[r].z & 0xFFFFu));
                const unsigned g3 = *(const unsigned*)((const char*)src + (q[r].w & 0xFFFFu));
                FMA_MIX_LO(a0[r], q[r].x, g0); FMA_MIX_HI(a1[r], q[r].x, g0);
                FMA_MIX_LO(b0[r], q[r].y, g1); FMA_MIX_HI(b1[r], q[r].y, g1);
                FMA_MIX_LO(a0[r], q[r].z, g2); FMA_MIX_HI(a1[r], q[r].z, g2);
                FMA_MIX_LO(b0[r], q[r].w, g3); FMA_MIX_HI(b1[r], q[r].w, g3);
                q[r] = qn[r];
            }
        }
#pragma unroll
        for (int r = 0; r < RPT; ++r) {
            const int v = r*THREADS + t;
            const float g0s = a0[r] + b0[r];
            const float g1s = a1[r] + b1[r];
            float xn0, xn1;
            if (first) { xn0 = g0s; xn1 = g1s; }
            else {
                const unsigned old = dst[v];          // own row's x_{k-2}
                xn0 = fmaf(2.f, g0s, -h2f_lo(old));
                xn1 = fmaf(2.f, g1s, -h2f_hi(old));
            }
            if (!last) {
                __half2 hh = __floats2half2_rn(xn0, xn1);
                dst[v] = *(const unsigned*)&hh;
            }
            const unsigned h0 = f2bf(xn0), h1 = f2bf(xn1);
            if (plane < 0) { tlo0[r] = h0; tlo1[r] = h1; }
            else {
                p0[(size_t)plane*V + v] = tlo0[r] | (h0 << 16);
                p1[(size_t)plane*V + v] = tlo1[r] | (h1 << 16);
            }
        }
        __syncthreads();
    };

    step(buf, buf + V, true, false, 0);                 // k=1, flush pair 0
    for (int k = 2; k < 24; k += 2) {
        step(buf + V, buf, false, false, -1);           // even k: stash
        step(buf, buf + V, false, false, (k + 1) >> 1); // odd k: flush pair
    }
    step(buf + V, buf, false, true, -1);                // k=24: stash only

#pragma unroll
    for (int r = 0; r < RPT; ++r) {                     // pair 12 = {bf16(x24), 0}
        const int v = r*THREADS + t;
        p0[(size_t)12*V + v] = tlo0[r];
        p1[(size_t)12*V + v] = tlo1[r];
    }
}

// ---------- layer-2 Chebyshev: 4 cols/block, f16x4 LDS ping-pong, interleaved rows ----------
template<int V, int THREADS, int MINW>
__global__ __launch_bounds__(THREADS, MINW) void k_cheb2(
        const float* __restrict__ X0T,
        const int* __restrict__ offs,
        const unsigned* __restrict__ ep,
        unsigned* __restrict__ stk) {
    constexpr int RPT = V / THREADS;     // 2
    __shared__ uint2 buf[2*V];
    const int c0 = blockIdx.x*4;
    const int t = threadIdx.x;
    int e0r[RPT], e1r[RPT];
    unsigned tlo[RPT][4];
    unsigned* __restrict__ pl[4];
#pragma unroll
    for (int j = 0; j < 4; ++j) pl[j] = stk + (size_t)(c0+j)*NP_*V;

#pragma unroll
    for (int r = 0; r < RPT; ++r) {
        const int v = r*THREADS + t;
        e0r[r] = offs[v]; e1r[r] = offs[v+1];
        float xj[4];
#pragma unroll
        for (int j = 0; j < 4; ++j) {
            xj[j] = X0T[(size_t)(c0+j)*V + v];
            tlo[r][j] = f2bf(xj[j]);
        }
        __half2 ha = __floats2half2_rn(xj[0], xj[1]);
        __half2 hb = __floats2half2_rn(xj[2], xj[3]);
        buf[v] = make_uint2(*(const unsigned*)&ha, *(const unsigned*)&hb);
    }
    __syncthreads();

    auto step = [&](const uint2* __restrict__ src, uint2* __restrict__ dst,
                    bool first, bool last, int plane) {
        // acc[row][col][chain]: chain0 <- edges x,z ; chain1 <- edges y,w
        float acc[RPT][4][2];
        uint4 q[RPT], qn[RPT];
        int mxp = 0;
#pragma unroll
        for (int r = 0; r < RPT; ++r) {
#pragma unroll
            for (int j = 0; j < 4; ++j) { acc[r][j][0] = 0.f; acc[r][j][1] = 0.f; }
            const int np = (e1r[r] - e0r[r]) >> 2;
            mxp = np > mxp ? np : mxp;
            q[r] = *(const uint4*)&ep[(e0r[r] < e1r[r]) ? e0r[r] : ZC2_];
        }
        for (int i = 0; i < mxp; ++i) {
#pragma unroll
            for (int r = 0; r < RPT; ++r) {
                const int e = e0r[r] + (i+1)*4;
                qn[r] = *(const uint4*)&ep[(e < e1r[r]) ? e : ZC2_];
            }
#pragma unroll
            for (int r = 0; r < RPT; ++r) {
                const uint2 g0 = *(const uint2*)((const char*)src + (q[r].x & 0xFFFFu));
                const uint2 g1 = *(const uint2*)((const char*)src + (q[r].y & 0xFFFFu));
                const uint2 g2 = *(const uint2*)((const char*)src + (q[r].z & 0xFFFFu));
                const uint2 g3 = *(const uint2*)((const char*)src + (q[r].w & 0xFFFFu));
                FMA_MIX_LO(acc[r][0][0], q[r].x, g0.x); FMA_MIX_HI(acc[r][1][0], q[r].x, g0.x);
                FMA_MIX_LO(acc[r][2][0], q[r].x, g0.y); FMA_MIX_HI(acc[r][3][0], q[r].x, g0.y);
                FMA_MIX_LO(acc[r][0][1], q[r].y, g1.x); FMA_MIX_HI(acc[r][1][1], q[r].y, g1.x);
                FMA_MIX_LO(acc[r][2][1], q[r].y, g1.y); FMA_MIX_HI(acc[r][3][1], q[r].y, g1.y);
                FMA_MIX_LO(acc[r][0][0], q[r].z, g2.x); FMA_MIX_HI(acc[r][1][0], q[r].z, g2.x);
                FMA_MIX_LO(acc[r][2][0], q[r].z, g2.y); FMA_MIX_HI(acc[r][3][0], q[r].z, g2.y);
                FMA_MIX_LO(acc[r][0][1], q[r].w, g3.x); FMA_MIX_HI(acc[r][1][1], q[r].w, g3.x);
                FMA_MIX_LO(acc[r][2][1], q[r].w, g3.y); FMA_MIX_HI(acc[r][3][1], q[r].w, g3.y);
                q[r] = qn[r];
            }
        }
#pragma unroll
        for (int r = 0; r < RPT; ++r) {
            const int v = r*THREADS + t;
            float gs[4], xn[4];
#pragma unroll
            for (int j = 0; j < 4; ++j) gs[j] = acc[r][j][0] + acc[r][j][1];
            if (first) {
#pragma unroll
                for (int j = 0; j < 4; ++j) xn[j] = gs[j];
            } else {
                const uint2 old = dst[v];
                xn[0] = fmaf(2.f, gs[0], -h2f_lo(old.x));
                xn[1] = fmaf(2.f, gs[1], -h2f_hi(old.x));
                xn[2] = fmaf(2.f, gs[2], -h2f_lo(old.y));
                xn[3] = fmaf(2.f, gs[3], -h2f_hi(old.y));
            }
            if (!last) {
                __half2 ha = __floats2half2_rn(xn[0], xn[1]);
                __half2 hb = __floats2half2_rn(xn[2], xn[3]);
                dst[v] = make_uint2(*(const unsigned*)&ha, *(const unsigned*)&hb);
            }
            unsigned h[4];
#pragma unroll
            for (int j = 0; j < 4; ++j) h[j] = f2bf(xn[j]);
            if (plane < 0) {
#pragma unroll
                for (int j = 0; j < 4; ++j) tlo[r][j] = h[j];
            } else {
#pragma unroll
                for (int j = 0; j < 4; ++j)
                    pl[j][(size_t)plane*V + v] = tlo[r][j] | (h[j] << 16);
            }
        }
        __syncthreads();
    };

    step(buf, buf + V, true, false, 0);
    for (int k = 2; k < 24; k += 2) {
        step(buf + V, buf, false, false, -1);
        step(buf, buf + V, false, false, (k + 1) >> 1);
    }
    step(buf + V, buf, false, true, -1);

#pragma unroll
    for (int r = 0; r < RPT; ++r) {
        const int v = r*THREADS + t;
#pragma unroll
        for (int j = 0; j < 4; ++j)
            pl[j][(size_t)12*V + v] = tlo[r][j];
    }
}

// ---------- W prep: Wb[fin][g][f][kk] = bf16(W[f][fin*25 + g*8+kk]), 0-padded ----------
template<int FIN, int F>
__global__ __launch_bounds__(256) void k_wprep(const float* __restrict__ W,
                                               unsigned short* __restrict__ Wb) {
    int idx = blockIdx.x*256 + threadIdx.x;
    int kk  = idx & 7;
    int f   = (idx >> 3) % F;
    int g   = (idx >> 3) / F % 4;
    int fin = idx / (8*F*4);
    int k = g*8 + kk;
    Wb[idx] = (k < K_) ? f2bf(W[(size_t)f*(FIN*K_) + fin*K_ + k]) : 0;
}

// ---------- layer-1 MFMA GEMM + relu + pool -> X0T2[(f*64+b)][v2] ----------
__global__ __launch_bounds__(256) void k_gemm1(const unsigned* __restrict__ STK,
                                               const unsigned short* __restrict__ Wb,
                                               const float* __restrict__ bias,
                                               float* __restrict__ X0T2) {
    __shared__ float Tsm[32][36];
    const int t = threadIdx.x, lane = t & 63, wave = t >> 6;
    const int b = blockIdx.x;
    const int v0 = blockIdx.y*128 + wave*32;
    const int m = lane & 15, g = lane >> 4;
    int offp[4];
#pragma unroll
    for (int p = 0; p < 4; ++p) {
        int pl = 4*g + p; if (pl > 12) pl = 12;   // clamp: k>=26 lands on pair12, Wb=0 kills it
        offp[p] = pl*V1_ + v0 + m;
    }

    f32x4 acc[2][2];
#pragma unroll
    for (int mt = 0; mt < 2; ++mt)
#pragma unroll
        for (int ft = 0; ft < 2; ++ft) acc[mt][ft] = (f32x4){0.f,0.f,0.f,0.f};

#pragma unroll
    for (int fin = 0; fin < DF_; ++fin) {
        const unsigned* sp = STK + (size_t)(fin*64 + b)*(NP_*V1_);
        unsigned ua[4], ub[4];
#pragma unroll
        for (int p = 0; p < 4; ++p) { ua[p] = sp[offp[p]]; ub[p] = sp[offp[p] + 16]; }
        bf16x8 a0, a1;
        __builtin_memcpy(&a0, ua, 16);
        __builtin_memcpy(&a1, ub, 16);
        const bf16x8 w0 = *(const bf16x8*)&Wb[((fin*4+g)*F1_ + m)*8];
        const bf16x8 w1 = *(const bf16x8*)&Wb[((fin*4+g)*F1_ + 16 + m)*8];
        acc[0][0] = __builtin_amdgcn_mfma_f32_16x16x32_bf16(a0, w0, acc[0][0], 0,0,0);
        acc[0][1] = __builtin_amdgcn_mfma_f32_16x16x32_bf16(a0, w1, acc[0][1], 0,0,0);
        acc[1][0] = __builtin_amdgcn_mfma_f32_16x16x32_bf16(a1, w0, acc[1][0], 0,0,0);
        acc[1][1] = __builtin_amdgcn_mfma_f32_16x16x32_bf16(a1, w1, acc[1][1], 0,0,0);
    }
    float bv[2] = { bias[m], bias[16+m] };
#pragma unroll
    for (int mt = 0; mt < 2; ++mt)
#pragma unroll
        for (int ft = 0; ft < 2; ++ft) {
            f32x4 a = acc[mt][ft];
            float mx = fmaxf(fmaxf(a[0],a[1]), fmaxf(a[2],a[3])) + bv[ft];
            Tsm[ft*16 + m][wave*8 + mt*4 + g] = fmaxf(mx, 0.f);
        }
    __syncthreads();
    const int f = t >> 3, vg = t & 7;
    float4 o = *(const float4*)&Tsm[f][vg*4];
    *(float4*)&X0T2[(size_t)(f*64+b)*V2_ + blockIdx.y*32 + vg*4] = o;
}

// ---------- layer-2 MFMA GEMM + relu + pool -> FCINT[v2*64+f][b] ----------
__global__ __launch_bounds__(256) void k_gemm2(const unsigned* __restrict__ STK,
                                               const unsigned short* __restrict__ Wb,
                                               const float* __restrict__ bias,
                                               float* __restrict__ FCINT) {
    const int t = threadIdx.x, lane = t & 63, wave = t >> 6;
    const int b = blockIdx.x;
    const int v0 = blockIdx.y*128 + wave*32;
    const int m = lane & 15, g = lane >> 4;
    int offp[4];
#pragma unroll
    for (int p = 0; p < 4; ++p) {
        int pl = 4*g + p; if (pl > 12) pl = 12;
        offp[p] = pl*V2_ + v0 + m;
    }

    f32x4 acc[2][4];
#pragma unroll
    for (int mt = 0; mt < 2; ++mt)
#pragma unroll
        for (int ft = 0; ft < 4; ++ft) acc[mt][ft] = (f32x4){0.f,0.f,0.f,0.f};

#pragma unroll 4
    for (int fin = 0; fin < F1_; ++fin) {
        const unsigned* sp = STK + (size_t)(fin*64 + b)*(NP_*V2_);
        unsigned ua[4], ub[4];
#pragma unroll
        for (int p = 0; p < 4; ++p) { ua[p] = sp[offp[p]]; ub[p] = sp[offp[p] + 16]; }
        bf16x8 a0, a1;
        __builtin_memcpy(&a0, ua, 16);
        __builtin_memcpy(&a1, ub, 16);
#pragma unroll
        for (int ft = 0; ft < 4; ++ft) {
            const bf16x8 bw = *(const bf16x8*)&Wb[((fin*4+g)*F2_ + ft*16 + m)*8];
            acc[0][ft] = __builtin_amdgcn_mfma_f32_16x16x32_bf16(a0, bw, acc[0][ft], 0,0,0);
            acc[1][ft] = __builtin_amdgcn_mfma_f32_16x16x32_bf16(a1, bw, acc[1][ft], 0,0,0);
        }
    }
#pragma unroll
    for (int mt = 0; mt < 2; ++mt)
#pragma unroll
        for (int ft = 0; ft < 4; ++ft) {
            f32x4 a = acc[mt][ft];
            float mx = fmaxf(fmaxf(a[0],a[1]), fmaxf(a[2],a[3])) + bias[ft*16 + m];
            mx = fmaxf(mx, 0.f);
            int v2 = blockIdx.y*32 + wave*8 + mt*4 + g;
            FCINT[((size_t)v2*64 + ft*16 + m)*64 + b] = mx;
        }
}

// ---------- FC1: O[b][j] (+= atomics over i-splits), AT layout [i][b] ----------
__global__ __launch_bounds__(256) void k_fc1_init(const float* __restrict__ bias,
                                                  float* __restrict__ O) {
    int idx = blockIdx.x*256 + threadIdx.x;
    O[idx] = bias[idx & (FC1F_-1)];
}

__global__ __launch_bounds__(256) void k_fc1(const float* __restrict__ AT,
                                             const float* __restrict__ W,
                                             float* __restrict__ O) {
    const int t = threadIdx.x;
    const int b = t & 63;
    const int jq = __builtin_amdgcn_readfirstlane(t >> 6);
    const int j0 = blockIdx.x*32 + jq*8;
    const int i0 = blockIdx.y*1024;
    float acc[8] = {};
    for (int i = i0; i < i0 + 1024; i += 4) {
        float a0 = AT[(size_t)(i+0)*64 + b];
        float a1 = AT[(size_t)(i+1)*64 + b];
        float a2 = AT[(size_t)(i+2)*64 + b];
        float a3 = AT[(size_t)(i+3)*64 + b];
#pragma unroll
        for (int jj = 0; jj < 8; ++jj) {
            const float* wp = &W[(size_t)(j0+jj)*FCIN_ + i];
            acc[jj] = fmaf(a0, wp[0], acc[jj]);
            acc[jj] = fmaf(a1, wp[1], acc[jj]);
            acc[jj] = fmaf(a2, wp[2], acc[jj]);
            acc[jj] = fmaf(a3, wp[3], acc[jj]);
        }
    }
#pragma unroll
    for (int jj = 0; jj < 8; ++jj)
        atomicAdd(&O[b*FC1F_ + j0 + jj], acc[jj]);
}

// ---------- FC2 (relu on FC1 output applied here) ----------
__global__ void k_fc2(const float* __restrict__ O1, const float* __restrict__ W2,
                      const float* __restrict__ b2, float* __restrict__ out) {
    int c = blockIdx.x;
    int b = threadIdx.x;
    float s = b2[c];
    for (int j = 0; j < FC1F_; ++j)
        s = fmaf(fmaxf(O1[b*FC1F_ + j], 0.f), W2[c*FC1F_ + j], s);
    out[b*FC2F_ + c] = s;
}

extern "C" void kernel_launch(void* const* d_in, const int* in_sizes, int n_in,
                              void* d_out, int out_size, void* d_ws, size_t ws_size,
                              hipStream_t stream) {
    const float* x   = (const float*)d_in[0];
    const int*   l1r = (const int*)d_in[1];
    const int*   l1c = (const int*)d_in[2];
    const float* l1v = (const float*)d_in[3];
    const int*   l2r = (const int*)d_in[4];
    const int*   l2c = (const int*)d_in[5];
    const float* l2v = (const float*)d_in[6];
    const float* w1  = (const float*)d_in[7];
    const float* b1  = (const float*)d_in[8];
    const float* w2  = (const float*)d_in[9];
    const float* b2  = (const float*)d_in[10];
    const float* fw1 = (const float*)d_in[11];
    const float* fb1 = (const float*)d_in[12];
    const float* fw2 = (const float*)d_in[13];
    const float* fb2 = (const float*)d_in[14];
    float* out = (float*)d_out;

    char* wsp = (char*)d_ws;
    size_t off = 0;
    auto alloc = [&](size_t bytes) -> void* {
        void* p = wsp + off;
        off += (bytes + 255) & ~size_t(255);
        return p;
    };
    float*    X0T1  = (float*)alloc((size_t)C1_*V1_*4);
    unsigned* STACK = (unsigned*)alloc((size_t)C1_*NP_*V1_*4);   // == C2_*NP_*V2_*4, reused
    float*    X0T2  = (float*)alloc((size_t)C2_*V2_*4);
    float*    FCINT = (float*)alloc((size_t)FCIN_*B_*4);
    float*    FC1O  = (float*)alloc((size_t)B_*FC1F_*4);
    unsigned short* WB1 = (unsigned short*)alloc((size_t)DF_*4*F1_*8*2);
    unsigned short* WB2 = (unsigned short*)alloc((size_t)F1_*4*F2_*8*2);
    int*      cnt1  = (int*)alloc(V1_*4);
    int*      offs1 = (int*)alloc((V1_+1)*4);
    int*      cur1  = (int*)alloc(V1_*4);
    unsigned* ep1   = (unsigned*)alloc((size_t)(E1_ + 4*V1_ + 8)*4);
    int*      cnt2  = (int*)alloc(V2_*4);
    int*      offs2 = (int*)alloc((V2_+1)*4);
    int*      cur2  = (int*)alloc(V2_*4);
    unsigned* ep2   = (unsigned*)alloc((size_t)(E2_ + 4*V2_ + 8)*4);

    // --- CSR build both layers + W prep ---
    hipMemsetAsync(cnt1, 0, V1_*4, stream);
    hipMemsetAsync(ep1, 0, (size_t)(E1_ + 4*V1_ + 8)*4, stream);
    hipMemsetAsync(cnt2, 0, V2_*4, stream);
    hipMemsetAsync(ep2, 0, (size_t)(E2_ + 4*V2_ + 8)*4, stream);
    hipLaunchKernelGGL(k_count,   dim3(E1_/256), dim3(256), 0, stream, l1r, E1_, cnt1);
    hipLaunchKernelGGL(k_scan,    dim3(1),       dim3(256), 0, stream, cnt1, V1_, offs1, cur1);
    hipLaunchKernelGGL(k_scatter, dim3(E1_/256), dim3(256), 0, stream, l1r, l1c, l1v, E1_, 2, cur1, ep1);
    hipLaunchKernelGGL(k_count,   dim3(E2_/256), dim3(256), 0, stream, l2r, E2_, cnt2);
    hipLaunchKernelGGL(k_scan,    dim3(1),       dim3(256), 0, stream, cnt2, V2_, offs2, cur2);
    hipLaunchKernelGGL(k_scatter, dim3(E2_/256), dim3(256), 0, stream, l2r, l2c, l2v, E2_, 3, cur2, ep2);
    hipLaunchKernelGGL((k_wprep<DF_,F1_>), dim3(DF_*4*F1_*8/256), dim3(256), 0, stream, w1, WB1);
    hipLaunchKernelGGL((k_wprep<F1_,F2_>), dim3(F1_*4*F2_*8/256), dim3(256), 0, stream, w2, WB2);

    // --- layer 1 ---
    hipLaunchKernelGGL(k_transpose_x, dim3(V1_/16), dim3(256), 0, stream, x, X0T1);
    hipLaunchKernelGGL((k_cheb1<V1_,1024,4>), dim3(C1_/2), dim3(1024), 0, stream,
                       X0T1, offs1, ep1, STACK);
    hipLaunchKernelGGL(k_gemm1, dim3(64, 32), dim3(256), 0, stream, STACK, WB1, b1, X0T2);

    // --- layer 2 ---
    hipLaunchKernelGGL((k_cheb2<V2_,512,4>), dim3(C2_/4), dim3(512), 0, stream,
                       X0T2, offs2, ep2, STACK);
    hipLaunchKernelGGL(k_gemm2, dim3(64, 8), dim3(256), 0, stream, STACK, WB2, b2, FCINT);

    // --- FC ---
    hipLaunchKernelGGL(k_fc1_init, dim3(B_*FC1F_/256), dim3(256), 0, stream, fb1, FC1O);
    hipLaunchKernelGGL(k_fc1, dim3(16, 16), dim3(256), 0, stream, FCINT, fw1, FC1O);
    hipLaunchKernelGGL(k_fc2, dim3(FC2F_), dim3(B_), 0, stream, FC1O, fw2, fb2, out);
}

// Round 11
// 630.110 us; speedup vs baseline: 1.6944x; 1.0816x over previous
//
#include <hip/hip_runtime.h>
#include <hip/hip_fp16.h>

#define B_    64
#define V1_   4096
#define V2_   1024
#define DF_   8
#define K_    25
#define NP_   13
#define F1_   32
#define F2_   64
#define FC1F_ 512
#define FC2F_ 10
#define E1_   65536
#define E2_   16384
#define C1_   512
#define C2_   2048
#define FCIN_ 16384

typedef short bf16x8 __attribute__((ext_vector_type(8)));
typedef float f32x4  __attribute__((ext_vector_type(4)));

// acc += f16(hi16 of q) * f16(lo16 of g)   [f32 accumulate]
#define FMA_MIX_LO(acc, qv, gv) \
    asm("v_fma_mix_f32 %0, %1, %2, %0 op_sel:[1,0,0] op_sel_hi:[1,1,0]" \
        : "+v"(acc) : "v"(qv), "v"(gv))
// acc += f16(hi16 of q) * f16(hi16 of g)
#define FMA_MIX_HI(acc, qv, gv) \
    asm("v_fma_mix_f32 %0, %1, %2, %0 op_sel:[1,1,0] op_sel_hi:[1,1,0]" \
        : "+v"(acc) : "v"(qv), "v"(gv))

__device__ __forceinline__ unsigned short f2bf(float x) {
    unsigned u = __float_as_uint(x);
    u += 0x7FFFu + ((u >> 16) & 1u);
    return (unsigned short)(u >> 16);
}
__device__ __forceinline__ float h2f_lo(unsigned u) {
    return __half2float(__ushort_as_half((unsigned short)(u & 0xFFFFu)));
}
__device__ __forceinline__ float h2f_hi(unsigned u) {
    return __half2float(__ushort_as_half((unsigned short)(u >> 16)));
}

// ---------- input transpose: x[b,v,fin] -> XP[v][c=fin*64+b] f16 + stk plane0 bf16 ----------
__global__ __launch_bounds__(256) void k_transpose_rm(const float* __restrict__ x,
                                                      unsigned* __restrict__ XP,
                                                      unsigned* __restrict__ stk0) {
    __shared__ float tsh[DF_][B_][16];
    const int t = threadIdx.x;
    const int v0 = blockIdx.x * 16;
    for (int rep = 0; rep < 4; ++rep) {
        int idx = rep*256 + t;
        int b = idx >> 4, vv = idx & 15;
        const float4* p = (const float4*)&x[((size_t)b*V1_ + v0 + vv)*DF_];
        float4 a0 = p[0], a1 = p[1];
        tsh[0][b][vv]=a0.x; tsh[1][b][vv]=a0.y; tsh[2][b][vv]=a0.z; tsh[3][b][vv]=a0.w;
        tsh[4][b][vv]=a1.x; tsh[5][b][vv]=a1.y; tsh[6][b][vv]=a1.z; tsh[7][b][vv]=a1.w;
    }
    __syncthreads();
    for (int rep = 0; rep < 16; ++rep) {
        int idx = rep*256 + t;            // 16 vv * 256 u32-pairs
        int c2 = idx & 255, vv = idx >> 8;
        int c = c2*2, fin = c >> 6, b = c & 63;
        float xa = tsh[fin][b][vv], xb = tsh[fin][b+1][vv];
        __half2 hh = __floats2half2_rn(xa, xb);
        XP[(size_t)(v0+vv)*256 + c2]   = *(const unsigned*)&hh;
        stk0[(size_t)(v0+vv)*256 + c2] = (unsigned)f2bf(xa) | ((unsigned)f2bf(xb) << 16);
    }
}

// ---------- CSR build (padded to 4-edge alignment, packed 4B edges) ----------
__global__ __launch_bounds__(256) void k_count(const int* __restrict__ rows, int E,
                                               int* __restrict__ cnt) {
    int e = blockIdx.x*256 + threadIdx.x;
    if (e < E) atomicAdd(&cnt[rows[e]], 1);
}

__global__ __launch_bounds__(256) void k_scan(const int* __restrict__ cnt, int V,
                                              int* __restrict__ offs, int* __restrict__ cursor) {
    __shared__ int psum[256];
    int t = threadIdx.x;
    int chunk = V >> 8;
    int lo = t*chunk;
    int s = 0;
    for (int i = lo; i < lo+chunk; ++i) s += (cnt[i] + 3) & ~3;
    psum[t] = s;
    __syncthreads();
    for (int off = 1; off < 256; off <<= 1) {
        int val = (t >= off) ? psum[t-off] : 0;
        __syncthreads();
        psum[t] += val;
        __syncthreads();
    }
    int run = (t == 0) ? 0 : psum[t-1];
    for (int i = lo; i < lo+chunk; ++i) {
        offs[i] = run; cursor[i] = run;
        run += (cnt[i] + 3) & ~3;
    }
    if (t == 255) offs[V] = run;
}

// edge payload: {f16 weight hi16, (col<<shift) lo16}
__global__ __launch_bounds__(256) void k_scatter(const int* __restrict__ rows,
                                                 const int* __restrict__ cols,
                                                 const float* __restrict__ vals, int E,
                                                 int shift,
                                                 int* __restrict__ cursor,
                                                 unsigned* __restrict__ ep) {
    int e = blockIdx.x*256 + threadIdx.x;
    if (e < E) {
        int p = atomicAdd(&cursor[rows[e]], 1);
        unsigned hv = (unsigned)__half_as_ushort(__float2half(vals[e]));
        ep[p] = (hv << 16) | ((unsigned)cols[e] << shift);
    }
}

// ---------- layer-1 dual Chebyshev step: 1 wave per row, all 512 cols ----------
// x_k = (k==1 ? L x0 : 2 L x_{k-1} - x_{k-2}); Xsrc = x_{k-1}, Xown = x_{k-2} in / x_k out.
// stk16[k][v][c] bf16.
__global__ __launch_bounds__(512) void k_dcheb1(int k,
        const unsigned short* __restrict__ Xsrc,
        unsigned short* __restrict__ Xown,
        unsigned short* __restrict__ stk16,
        const int* __restrict__ offs,
        const unsigned* __restrict__ ep) {
    const int t = threadIdx.x;
    const int lane = t & 63;
    const int v = blockIdx.x*8 + (t >> 6);
    const int e0 = offs[v], e1 = offs[v+1];
    const unsigned loff = (unsigned)lane * 16u;
    float acc[8];
#pragma unroll
    for (int j = 0; j < 8; ++j) acc[j] = 0.f;
    const char* srcb = (const char*)Xsrc;

    for (int e = e0; e < e1; e += 4) {
        const uint4 q = *(const uint4*)&ep[e];
        const uint4 g0 = *(const uint4*)(srcb + ((q.x & 0xFFFFu)*1024u + loff));
        const uint4 g1 = *(const uint4*)(srcb + ((q.y & 0xFFFFu)*1024u + loff));
        const uint4 g2 = *(const uint4*)(srcb + ((q.z & 0xFFFFu)*1024u + loff));
        const uint4 g3 = *(const uint4*)(srcb + ((q.w & 0xFFFFu)*1024u + loff));
        FMA_MIX_LO(acc[0], q.x, g0.x); FMA_MIX_HI(acc[1], q.x, g0.x);
        FMA_MIX_LO(acc[2], q.x, g0.y); FMA_MIX_HI(acc[3], q.x, g0.y);
        FMA_MIX_LO(acc[4], q.x, g0.z); FMA_MIX_HI(acc[5], q.x, g0.z);
        FMA_MIX_LO(acc[6], q.x, g0.w); FMA_MIX_HI(acc[7], q.x, g0.w);
        FMA_MIX_LO(acc[0], q.y, g1.x); FMA_MIX_HI(acc[1], q.y, g1.x);
        FMA_MIX_LO(acc[2], q.y, g1.y); FMA_MIX_HI(acc[3], q.y, g1.y);
        FMA_MIX_LO(acc[4], q.y, g1.z); FMA_MIX_HI(acc[5], q.y, g1.z);
        FMA_MIX_LO(acc[6], q.y, g1.w); FMA_MIX_HI(acc[7], q.y, g1.w);
        FMA_MIX_LO(acc[0], q.z, g2.x); FMA_MIX_HI(acc[1], q.z, g2.x);
        FMA_MIX_LO(acc[2], q.z, g2.y); FMA_MIX_HI(acc[3], q.z, g2.y);
        FMA_MIX_LO(acc[4], q.z, g2.z); FMA_MIX_HI(acc[5], q.z, g2.z);
        FMA_MIX_LO(acc[6], q.z, g2.w); FMA_MIX_HI(acc[7], q.z, g2.w);
        FMA_MIX_LO(acc[0], q.w, g3.x); FMA_MIX_HI(acc[1], q.w, g3.x);
        FMA_MIX_LO(acc[2], q.w, g3.y); FMA_MIX_HI(acc[3], q.w, g3.y);
        FMA_MIX_LO(acc[4], q.w, g3.z); FMA_MIX_HI(acc[5], q.w, g3.z);
        FMA_MIX_LO(acc[6], q.w, g3.w); FMA_MIX_HI(acc[7], q.w, g3.w);
    }

    float xn[8];
    if (k > 1) {
        const uint4 old = *(const uint4*)((const char*)Xown + ((size_t)v*1024 + loff));
        xn[0] = fmaf(2.f, acc[0], -h2f_lo(old.x));
        xn[1] = fmaf(2.f, acc[1], -h2f_hi(old.x));
        xn[2] = fmaf(2.f, acc[2], -h2f_lo(old.y));
        xn[3] = fmaf(2.f, acc[3], -h2f_hi(old.y));
        xn[4] = fmaf(2.f, acc[4], -h2f_lo(old.z));
        xn[5] = fmaf(2.f, acc[5], -h2f_hi(old.z));
        xn[6] = fmaf(2.f, acc[6], -h2f_lo(old.w));
        xn[7] = fmaf(2.f, acc[7], -h2f_hi(old.w));
    } else {
#pragma unroll
        for (int j = 0; j < 8; ++j) xn[j] = acc[j];
    }

    uint4 hp;
    { __half2 h0 = __floats2half2_rn(xn[0], xn[1]); hp.x = *(const unsigned*)&h0;
      __half2 h1 = __floats2half2_rn(xn[2], xn[3]); hp.y = *(const unsigned*)&h1;
      __half2 h2 = __floats2half2_rn(xn[4], xn[5]); hp.z = *(const unsigned*)&h2;
      __half2 h3 = __floats2half2_rn(xn[6], xn[7]); hp.w = *(const unsigned*)&h3; }
    *(uint4*)((char*)Xown + ((size_t)v*1024 + loff)) = hp;

    uint4 bp;
    bp.x = (unsigned)f2bf(xn[0]) | ((unsigned)f2bf(xn[1]) << 16);
    bp.y = (unsigned)f2bf(xn[2]) | ((unsigned)f2bf(xn[3]) << 16);
    bp.z = (unsigned)f2bf(xn[4]) | ((unsigned)f2bf(xn[5]) << 16);
    bp.w = (unsigned)f2bf(xn[6]) | ((unsigned)f2bf(xn[7]) << 16);
    *(uint4*)((char*)stk16 + (((size_t)k*V1_ + v)*1024 + loff)) = bp;
}

// ---------- W prep: Wb[fin][g][f][kk] = bf16(W[f][fin*25 + g*8+kk]), 0-padded ----------
template<int FIN, int F>
__global__ __launch_bounds__(256) void k_wprep(const float* __restrict__ W,
                                               unsigned short* __restrict__ Wb) {
    int idx = blockIdx.x*256 + threadIdx.x;
    int kk  = idx & 7;
    int f   = (idx >> 3) % F;
    int g   = (idx >> 3) / F % 4;
    int fin = idx / (8*F*4);
    int k = g*8 + kk;
    Wb[idx] = (k < K_) ? f2bf(W[(size_t)f*(FIN*K_) + fin*K_ + k]) : 0;
}

// ---------- layer-1 MFMA GEMM (stk16 [k][v][c] layout) + relu + pool -> X0T2[(f*64+b)][v2]
// block = 256 thr = 4 waves; wave w owns v2 = blk*4 + w; M=b (4 tiles), N=f (2 tiles).
__global__ __launch_bounds__(256) void k_gemm1b(const unsigned short* __restrict__ stk16,
                                                const unsigned short* __restrict__ Wb,
                                                const float* __restrict__ bias,
                                                float* __restrict__ X0T2) {
    const int t = threadIdx.x, lane = t & 63, wave = t >> 6;
    const int v2 = blockIdx.x*4 + wave;
    const int m = lane & 15, g = lane >> 4;
    int kbase[8];
#pragma unroll
    for (int j = 0; j < 8; ++j) {
        int kq = g*8 + j; if (kq > 24) kq = 24;     // Wb=0 for k>=25 kills the clamp reads
        kbase[j] = kq * (V1_*C1_);
    }
    float bv[2] = { bias[m], bias[16+m] };
    f32x4 pool[4][2];

    for (int vv = 0; vv < 4; ++vv) {
        const int v = v2*4 + vv;
        f32x4 acc[4][2];
#pragma unroll
        for (int mt = 0; mt < 4; ++mt)
#pragma unroll
            for (int ft = 0; ft < 2; ++ft) acc[mt][ft] = (f32x4){0.f,0.f,0.f,0.f};

        for (int fin = 0; fin < DF_; ++fin) {
            const int cbase = v*C1_ + fin*64 + m;
            const bf16x8 bw0 = *(const bf16x8*)&Wb[((fin*4+g)*F1_ + m)*8];
            const bf16x8 bw1 = *(const bf16x8*)&Wb[((fin*4+g)*F1_ + 16 + m)*8];
#pragma unroll
            for (int mt = 0; mt < 4; ++mt) {
                unsigned short au[8];
#pragma unroll
                for (int j = 0; j < 8; ++j)
                    au[j] = stk16[(size_t)(kbase[j] + cbase + mt*16)];
                bf16x8 a;
                __builtin_memcpy(&a, au, 16);
                acc[mt][0] = __builtin_amdgcn_mfma_f32_16x16x32_bf16(a, bw0, acc[mt][0], 0,0,0);
                acc[mt][1] = __builtin_amdgcn_mfma_f32_16x16x32_bf16(a, bw1, acc[mt][1], 0,0,0);
            }
        }
#pragma unroll
        for (int mt = 0; mt < 4; ++mt)
#pragma unroll
            for (int ft = 0; ft < 2; ++ft) {
                if (vv == 0) pool[mt][ft] = acc[mt][ft];
                else {
#pragma unroll
                    for (int j = 0; j < 4; ++j)
                        pool[mt][ft][j] = fmaxf(pool[mt][ft][j], acc[mt][ft][j]);
                }
            }
    }

#pragma unroll
    for (int mt = 0; mt < 4; ++mt)
#pragma unroll
        for (int ft = 0; ft < 2; ++ft)
#pragma unroll
            for (int j = 0; j < 4; ++j) {
                float mx = fmaxf(pool[mt][ft][j] + bv[ft], 0.f);
                int b = mt*16 + g*4 + j;       // C/D: row = (lane>>4)*4 + j
                int f = ft*16 + m;             // C/D: col = lane&15
                X0T2[(size_t)(f*64+b)*V2_ + v2] = mx;
            }
}

// ---------- layer-2 Chebyshev: 4 cols/block, f16x4 LDS ping-pong (r8 version) ----------
template<int V, int THREADS, int MINW>
__global__ __launch_bounds__(THREADS, MINW) void k_cheb2(
        const float* __restrict__ X0T,
        const int* __restrict__ offs,
        const unsigned* __restrict__ ep,
        unsigned* __restrict__ stk) {
    constexpr int RPT = V / THREADS;     // 2
    __shared__ uint2 buf[2*V];
    const int c0 = blockIdx.x*4;
    const int t = threadIdx.x;
    int e0r[RPT], e1r[RPT];
    unsigned tlo[RPT][4];
    unsigned* __restrict__ pl[4];
#pragma unroll
    for (int j = 0; j < 4; ++j) pl[j] = stk + (size_t)(c0+j)*NP_*V;

#pragma unroll
    for (int r = 0; r < RPT; ++r) {
        const int v = r*THREADS + t;
        e0r[r] = offs[v]; e1r[r] = offs[v+1];
        float xj[4];
#pragma unroll
        for (int j = 0; j < 4; ++j) {
            xj[j] = X0T[(size_t)(c0+j)*V + v];
            tlo[r][j] = f2bf(xj[j]);
        }
        __half2 ha = __floats2half2_rn(xj[0], xj[1]);
        __half2 hb = __floats2half2_rn(xj[2], xj[3]);
        buf[v] = make_uint2(*(const unsigned*)&ha, *(const unsigned*)&hb);
    }
    __syncthreads();

    auto step = [&](const uint2* __restrict__ src, uint2* __restrict__ dst,
                    bool first, bool last, int plane) {
#pragma unroll
        for (int r = 0; r < RPT; ++r) {
            const int v = r*THREADS + t;
            float acc[4][4];
#pragma unroll
            for (int j = 0; j < 4; ++j)
#pragma unroll
                for (int i = 0; i < 4; ++i) acc[j][i] = 0.f;
            const int ee0 = e0r[r], ee1 = e1r[r];
            uint4 q = *(const uint4*)&ep[ee0];
            for (int e = ee0; e < ee1; e += 4) {
                const uint4 qn = *(const uint4*)&ep[e + 4];
                const uint2 g0 = *(const uint2*)((const char*)src + (q.x & 0xFFFFu));
                const uint2 g1 = *(const uint2*)((const char*)src + (q.y & 0xFFFFu));
                const uint2 g2 = *(const uint2*)((const char*)src + (q.z & 0xFFFFu));
                const uint2 g3 = *(const uint2*)((const char*)src + (q.w & 0xFFFFu));
                FMA_MIX_LO(acc[0][0], q.x, g0.x); FMA_MIX_HI(acc[1][0], q.x, g0.x);
                FMA_MIX_LO(acc[2][0], q.x, g0.y); FMA_MIX_HI(acc[3][0], q.x, g0.y);
                FMA_MIX_LO(acc[0][1], q.y, g1.x); FMA_MIX_HI(acc[1][1], q.y, g1.x);
                FMA_MIX_LO(acc[2][1], q.y, g1.y); FMA_MIX_HI(acc[3][1], q.y, g1.y);
                FMA_MIX_LO(acc[0][2], q.z, g2.x); FMA_MIX_HI(acc[1][2], q.z, g2.x);
                FMA_MIX_LO(acc[2][2], q.z, g2.y); FMA_MIX_HI(acc[3][2], q.z, g2.y);
                FMA_MIX_LO(acc[0][3], q.w, g3.x); FMA_MIX_HI(acc[1][3], q.w, g3.x);
                FMA_MIX_LO(acc[2][3], q.w, g3.y); FMA_MIX_HI(acc[3][3], q.w, g3.y);
                q = qn;
            }
            float gs[4];
#pragma unroll
            for (int j = 0; j < 4; ++j)
                gs[j] = (acc[j][0]+acc[j][1])+(acc[j][2]+acc[j][3]);
            float xn[4];
            if (first) {
#pragma unroll
                for (int j = 0; j < 4; ++j) xn[j] = gs[j];
            } else {
                const uint2 old = dst[v];
                xn[0] = fmaf(2.f, gs[0], -h2f_lo(old.x));
                xn[1] = fmaf(2.f, gs[1], -h2f_hi(old.x));
                xn[2] = fmaf(2.f, gs[2], -h2f_lo(old.y));
                xn[3] = fmaf(2.f, gs[3], -h2f_hi(old.y));
            }
            if (!last) {
                __half2 ha = __floats2half2_rn(xn[0], xn[1]);
                __half2 hb = __floats2half2_rn(xn[2], xn[3]);
                dst[v] = make_uint2(*(const unsigned*)&ha, *(const unsigned*)&hb);
            }
            unsigned h[4];
#pragma unroll
            for (int j = 0; j < 4; ++j) h[j] = f2bf(xn[j]);
            if (plane < 0) {
#pragma unroll
                for (int j = 0; j < 4; ++j) tlo[r][j] = h[j];
            } else {
#pragma unroll
                for (int j = 0; j < 4; ++j)
                    pl[j][(size_t)plane*V + v] = tlo[r][j] | (h[j] << 16);
            }
        }
        __syncthreads();
    };

    step(buf, buf + V, true, false, 0);
    for (int k = 2; k < 24; k += 2) {
        step(buf + V, buf, false, false, -1);
        step(buf, buf + V, false, false, (k + 1) >> 1);
    }
    step(buf + V, buf, false, true, -1);

#pragma unroll
    for (int r = 0; r < RPT; ++r) {
        const int v = r*THREADS + t;
#pragma unroll
        for (int j = 0; j < 4; ++j)
            pl[j][(size_t)12*V + v] = tlo[r][j];
    }
}

// ---------- layer-2 MFMA GEMM + relu + pool -> FCINT[v2*64+f][b] ----------
__global__ __launch_bounds__(256) void k_gemm2(const unsigned* __restrict__ STK,
                                               const unsigned short* __restrict__ Wb,
                                               const float* __restrict__ bias,
                                               float* __restrict__ FCINT) {
    const int t = threadIdx.x, lane = t & 63, wave = t >> 6;
    const int b = blockIdx.x;
    const int v0 = blockIdx.y*128 + wave*32;
    const int m = lane & 15, g = lane >> 4;
    int offp[4];
#pragma unroll
    for (int p = 0; p < 4; ++p) {
        int pl = 4*g + p; if (pl > 12) pl = 12;
        offp[p] = pl*V2_ + v0 + m;
    }

    f32x4 acc[2][4];
#pragma unroll
    for (int mt = 0; mt < 2; ++mt)
#pragma unroll
        for (int ft = 0; ft < 4; ++ft) acc[mt][ft] = (f32x4){0.f,0.f,0.f,0.f};

#pragma unroll 4
    for (int fin = 0; fin < F1_; ++fin) {
        const unsigned* sp = STK + (size_t)(fin*64 + b)*(NP_*V2_);
        unsigned ua[4], ub[4];
#pragma unroll
        for (int p = 0; p < 4; ++p) { ua[p] = sp[offp[p]]; ub[p] = sp[offp[p] + 16]; }
        bf16x8 a0, a1;
        __builtin_memcpy(&a0, ua, 16);
        __builtin_memcpy(&a1, ub, 16);
#pragma unroll
        for (int ft = 0; ft < 4; ++ft) {
            const bf16x8 bw = *(const bf16x8*)&Wb[((fin*4+g)*F2_ + ft*16 + m)*8];
            acc[0][ft] = __builtin_amdgcn_mfma_f32_16x16x32_bf16(a0, bw, acc[0][ft], 0,0,0);
            acc[1][ft] = __builtin_amdgcn_mfma_f32_16x16x32_bf16(a1, bw, acc[1][ft], 0,0,0);
        }
    }
#pragma unroll
    for (int mt = 0; mt < 2; ++mt)
#pragma unroll
        for (int ft = 0; ft < 4; ++ft) {
            f32x4 a = acc[mt][ft];
            float mx = fmaxf(fmaxf(a[0],a[1]), fmaxf(a[2],a[3])) + bias[ft*16 + m];
            mx = fmaxf(mx, 0.f);
            int v2 = blockIdx.y*32 + wave*8 + mt*4 + g;
            FCINT[((size_t)v2*64 + ft*16 + m)*64 + b] = mx;
        }
}

// ---------- FC1: O[b][j] (+= atomics over i-splits), AT layout [i][b] ----------
__global__ __launch_bounds__(256) void k_fc1_init(const float* __restrict__ bias,
                                                  float* __restrict__ O) {
    int idx = blockIdx.x*256 + threadIdx.x;
    O[idx] = bias[idx & (FC1F_-1)];
}

__global__ __launch_bounds__(256) void k_fc1(const float* __restrict__ AT,
                                             const float* __restrict__ W,
                                             float* __restrict__ O) {
    const int t = threadIdx.x;
    const int b = t & 63;
    const int jq = __builtin_amdgcn_readfirstlane(t >> 6);
    const int j0 = blockIdx.x*32 + jq*8;
    const int i0 = blockIdx.y*1024;
    float acc[8] = {};
    for (int i = i0; i < i0 + 1024; i += 4) {
        float a0 = AT[(size_t)(i+0)*64 + b];
        float a1 = AT[(size_t)(i+1)*64 + b];
        float a2 = AT[(size_t)(i+2)*64 + b];
        float a3 = AT[(size_t)(i+3)*64 + b];
#pragma unroll
        for (int jj = 0; jj < 8; ++jj) {
            const float* wp = &W[(size_t)(j0+jj)*FCIN_ + i];
            acc[jj] = fmaf(a0, wp[0], acc[jj]);
            acc[jj] = fmaf(a1, wp[1], acc[jj]);
            acc[jj] = fmaf(a2, wp[2], acc[jj]);
            acc[jj] = fmaf(a3, wp[3], acc[jj]);
        }
    }
#pragma unroll
    for (int jj = 0; jj < 8; ++jj)
        atomicAdd(&O[b*FC1F_ + j0 + jj], acc[jj]);
}

// ---------- FC2 (relu on FC1 output applied here) ----------
__global__ void k_fc2(const float* __restrict__ O1, const float* __restrict__ W2,
                      const float* __restrict__ b2, float* __restrict__ out) {
    int c = blockIdx.x;
    int b = threadIdx.x;
    float s = b2[c];
    for (int j = 0; j < FC1F_; ++j)
        s = fmaf(fmaxf(O1[b*FC1F_ + j], 0.f), W2[c*FC1F_ + j], s);
    out[b*FC2F_ + c] = s;
}

extern "C" void kernel_launch(void* const* d_in, const int* in_sizes, int n_in,
                              void* d_out, int out_size, void* d_ws, size_t ws_size,
                              hipStream_t stream) {
    const float* x   = (const float*)d_in[0];
    const int*   l1r = (const int*)d_in[1];
    const int*   l1c = (const int*)d_in[2];
    const float* l1v = (const float*)d_in[3];
    const int*   l2r = (const int*)d_in[4];
    const int*   l2c = (const int*)d_in[5];
    const float* l2v = (const float*)d_in[6];
    const float* w1  = (const float*)d_in[7];
    const float* b1  = (const float*)d_in[8];
    const float* w2  = (const float*)d_in[9];
    const float* b2  = (const float*)d_in[10];
    const float* fw1 = (const float*)d_in[11];
    const float* fb1 = (const float*)d_in[12];
    const float* fw2 = (const float*)d_in[13];
    const float* fb2 = (const float*)d_in[14];
    float* out = (float*)d_out;

    char* wsp = (char*)d_ws;
    size_t off = 0;
    auto alloc = [&](size_t bytes) -> void* {
        void* p = wsp + off;
        off += (bytes + 255) & ~size_t(255);
        return p;
    };
    // shared big buffer: stk16 (layer-1, 25*V1*C1*2 = 100MB) then STACK (layer-2, 109MB).
    // gemm1b finishes reading stk16 before cheb2 writes STACK (stream-ordered).
    void*     STKU  = alloc((size_t)C2_*NP_*V2_*4);                 // 109 MB
    unsigned short* stk16 = (unsigned short*)STKU;
    unsigned*       STACK = (unsigned*)STKU;
    unsigned short* XB0   = (unsigned short*)alloc((size_t)V1_*C1_*2);  // 4 MB
    unsigned short* XB1   = (unsigned short*)alloc((size_t)V1_*C1_*2);  // 4 MB
    float*    X0T2  = (float*)alloc((size_t)C2_*V2_*4);             // 8 MB
    float*    FCINT = (float*)alloc((size_t)FCIN_*B_*4);
    float*    FC1O  = (float*)alloc((size_t)B_*FC1F_*4);
    unsigned short* WB1 = (unsigned short*)alloc((size_t)DF_*4*F1_*8*2);
    unsigned short* WB2 = (unsigned short*)alloc((size_t)F1_*4*F2_*8*2);
    int*      cnt1  = (int*)alloc(V1_*4);
    int*      offs1 = (int*)alloc((V1_+1)*4);
    int*      cur1  = (int*)alloc(V1_*4);
    unsigned* ep1   = (unsigned*)alloc((size_t)(E1_ + 4*V1_ + 8)*4);
    int*      cnt2  = (int*)alloc(V2_*4);
    int*      offs2 = (int*)alloc((V2_+1)*4);
    int*      cur2  = (int*)alloc(V2_*4);
    unsigned* ep2   = (unsigned*)alloc((size_t)(E2_ + 4*V2_ + 8)*4);

    // --- CSR build both layers + W prep ---
    hipMemsetAsync(cnt1, 0, V1_*4, stream);
    hipMemsetAsync(ep1, 0, (size_t)(E1_ + 4*V1_ + 8)*4, stream);
    hipMemsetAsync(cnt2, 0, V2_*4, stream);
    hipMemsetAsync(ep2, 0, (size_t)(E2_ + 4*V2_ + 8)*4, stream);
    hipLaunchKernelGGL(k_count,   dim3(E1_/256), dim3(256), 0, stream, l1r, E1_, cnt1);
    hipLaunchKernelGGL(k_scan,    dim3(1),       dim3(256), 0, stream, cnt1, V1_, offs1, cur1);
    hipLaunchKernelGGL(k_scatter, dim3(E1_/256), dim3(256), 0, stream, l1r, l1c, l1v, E1_, 0, cur1, ep1);
    hipLaunchKernelGGL(k_count,   dim3(E2_/256), dim3(256), 0, stream, l2r, E2_, cnt2);
    hipLaunchKernelGGL(k_scan,    dim3(1),       dim3(256), 0, stream, cnt2, V2_, offs2, cur2);
    hipLaunchKernelGGL(k_scatter, dim3(E2_/256), dim3(256), 0, stream, l2r, l2c, l2v, E2_, 3, cur2, ep2);
    hipLaunchKernelGGL((k_wprep<DF_,F1_>), dim3(DF_*4*F1_*8/256), dim3(256), 0, stream, w1, WB1);
    hipLaunchKernelGGL((k_wprep<F1_,F2_>), dim3(F1_*4*F2_*8/256), dim3(256), 0, stream, w2, WB2);

    // --- layer 1: dual-cheb, one launch per k-step ---
    hipLaunchKernelGGL(k_transpose_rm, dim3(V1_/16), dim3(256), 0, stream,
                       x, (unsigned*)XB0, (unsigned*)stk16);
    for (int k = 1; k <= 24; ++k) {
        unsigned short* src = (k & 1) ? XB0 : XB1;   // x_{k-1}
        unsigned short* own = (k & 1) ? XB1 : XB0;   // x_{k-2} in, x_k out
        hipLaunchKernelGGL(k_dcheb1, dim3(V1_/8), dim3(512), 0, stream,
                           k, src, own, stk16, offs1, ep1);
    }
    hipLaunchKernelGGL(k_gemm1b, dim3(V2_/4), dim3(256), 0, stream, stk16, WB1, b1, X0T2);

    // --- layer 2 (r8 structure) ---
    hipLaunchKernelGGL((k_cheb2<V2_,512,4>), dim3(C2_/4), dim3(512), 0, stream,
                       X0T2, offs2, ep2, STACK);
    hipLaunchKernelGGL(k_gemm2, dim3(64, 8), dim3(256), 0, stream, STACK, WB2, b2, FCINT);

    // --- FC ---
    hipLaunchKernelGGL(k_fc1_init, dim3(B_*FC1F_/256), dim3(256), 0, stream, fb1, FC1O);
    hipLaunchKernelGGL(k_fc1, dim3(16, 16), dim3(256), 0, stream, FCINT, fw1, FC1O);
    hipLaunchKernelGGL(k_fc2, dim3(FC2F_), dim3(B_), 0, stream, FC1O, fw2, fb2, out);
}

// Round 12
// 520.842 us; speedup vs baseline: 2.0498x; 1.2098x over previous
//
#include <hip/hip_runtime.h>
#include <hip/hip_fp16.h>

#define B_    64
#define V1_   4096
#define V2_   1024
#define DF_   8
#define K_    25
#define NP_   13
#define F1_   32
#define F2_   64
#define FC1F_ 512
#define FC2F_ 10
#define E1_   65536
#define E2_   16384
#define C1_   512
#define C2_   2048
#define FCIN_ 16384

typedef short bf16x8 __attribute__((ext_vector_type(8)));
typedef float f32x4  __attribute__((ext_vector_type(4)));

// acc += f16(hi16 of q) * f16(lo16 of g)   [f32 accumulate]
#define FMA_MIX_LO(acc, qv, gv) \
    asm("v_fma_mix_f32 %0, %1, %2, %0 op_sel:[1,0,0] op_sel_hi:[1,1,0]" \
        : "+v"(acc) : "v"(qv), "v"(gv))
// acc += f16(hi16 of q) * f16(hi16 of g)
#define FMA_MIX_HI(acc, qv, gv) \
    asm("v_fma_mix_f32 %0, %1, %2, %0 op_sel:[1,1,0] op_sel_hi:[1,1,0]" \
        : "+v"(acc) : "v"(qv), "v"(gv))

__device__ __forceinline__ unsigned short f2bf(float x) {
    unsigned u = __float_as_uint(x);
    u += 0x7FFFu + ((u >> 16) & 1u);
    return (unsigned short)(u >> 16);
}
__device__ __forceinline__ float h2f_lo(unsigned u) {
    return __half2float(__ushort_as_half((unsigned short)(u & 0xFFFFu)));
}
__device__ __forceinline__ float h2f_hi(unsigned u) {
    return __half2float(__ushort_as_half((unsigned short)(u >> 16)));
}

// ---------- input transpose: x[b,v,fin] -> XP[v][c=fin*64+b] f16 + stk plane0 bf16 ----------
__global__ __launch_bounds__(256) void k_transpose_rm(const float* __restrict__ x,
                                                      unsigned* __restrict__ XP,
                                                      unsigned* __restrict__ stk0) {
    __shared__ float tsh[DF_][B_][16];
    const int t = threadIdx.x;
    const int v0 = blockIdx.x * 16;
    for (int rep = 0; rep < 4; ++rep) {
        int idx = rep*256 + t;
        int b = idx >> 4, vv = idx & 15;
        const float4* p = (const float4*)&x[((size_t)b*V1_ + v0 + vv)*DF_];
        float4 a0 = p[0], a1 = p[1];
        tsh[0][b][vv]=a0.x; tsh[1][b][vv]=a0.y; tsh[2][b][vv]=a0.z; tsh[3][b][vv]=a0.w;
        tsh[4][b][vv]=a1.x; tsh[5][b][vv]=a1.y; tsh[6][b][vv]=a1.z; tsh[7][b][vv]=a1.w;
    }
    __syncthreads();
    for (int rep = 0; rep < 16; ++rep) {
        int idx = rep*256 + t;
        int c2 = idx & 255, vv = idx >> 8;
        int c = c2*2, fin = c >> 6, b = c & 63;
        float xa = tsh[fin][b][vv], xb = tsh[fin][b+1][vv];
        __half2 hh = __floats2half2_rn(xa, xb);
        XP[(size_t)(v0+vv)*256 + c2]   = *(const unsigned*)&hh;
        stk0[(size_t)(v0+vv)*256 + c2] = (unsigned)f2bf(xa) | ((unsigned)f2bf(xb) << 16);
    }
}

// ---------- CSR build (padded to 4-edge alignment, packed 4B edges) ----------
__global__ __launch_bounds__(256) void k_count(const int* __restrict__ rows, int E,
                                               int* __restrict__ cnt) {
    int e = blockIdx.x*256 + threadIdx.x;
    if (e < E) atomicAdd(&cnt[rows[e]], 1);
}

__global__ __launch_bounds__(256) void k_scan(const int* __restrict__ cnt, int V,
                                              int* __restrict__ offs, int* __restrict__ cursor) {
    __shared__ int psum[256];
    int t = threadIdx.x;
    int chunk = V >> 8;
    int lo = t*chunk;
    int s = 0;
    for (int i = lo; i < lo+chunk; ++i) s += (cnt[i] + 3) & ~3;
    psum[t] = s;
    __syncthreads();
    for (int off = 1; off < 256; off <<= 1) {
        int val = (t >= off) ? psum[t-off] : 0;
        __syncthreads();
        psum[t] += val;
        __syncthreads();
    }
    int run = (t == 0) ? 0 : psum[t-1];
    for (int i = lo; i < lo+chunk; ++i) {
        offs[i] = run; cursor[i] = run;
        run += (cnt[i] + 3) & ~3;
    }
    if (t == 255) offs[V] = run;
}

// edge payload: {f16 weight hi16, (col<<shift) lo16}
__global__ __launch_bounds__(256) void k_scatter(const int* __restrict__ rows,
                                                 const int* __restrict__ cols,
                                                 const float* __restrict__ vals, int E,
                                                 int shift,
                                                 int* __restrict__ cursor,
                                                 unsigned* __restrict__ ep) {
    int e = blockIdx.x*256 + threadIdx.x;
    if (e < E) {
        int p = atomicAdd(&cursor[rows[e]], 1);
        unsigned hv = (unsigned)__half_as_ushort(__float2half(vals[e]));
        ep[p] = (hv << 16) | ((unsigned)cols[e] << shift);
    }
}

// ---------- layer-1 dual Chebyshev step: 1 wave per row, all 512 cols ----------
__global__ __launch_bounds__(512) void k_dcheb1(int k,
        const unsigned short* __restrict__ Xsrc,
        unsigned short* __restrict__ Xown,
        unsigned short* __restrict__ stk16,
        const int* __restrict__ offs,
        const unsigned* __restrict__ ep) {
    const int t = threadIdx.x;
    const int lane = t & 63;
    const int v = blockIdx.x*8 + (t >> 6);
    const int e0 = offs[v], e1 = offs[v+1];
    const unsigned loff = (unsigned)lane * 16u;
    float acc[8];
#pragma unroll
    for (int j = 0; j < 8; ++j) acc[j] = 0.f;
    const char* srcb = (const char*)Xsrc;

    for (int e = e0; e < e1; e += 4) {
        const uint4 q = *(const uint4*)&ep[e];
        const uint4 g0 = *(const uint4*)(srcb + ((q.x & 0xFFFFu)*1024u + loff));
        const uint4 g1 = *(const uint4*)(srcb + ((q.y & 0xFFFFu)*1024u + loff));
        const uint4 g2 = *(const uint4*)(srcb + ((q.z & 0xFFFFu)*1024u + loff));
        const uint4 g3 = *(const uint4*)(srcb + ((q.w & 0xFFFFu)*1024u + loff));
        FMA_MIX_LO(acc[0], q.x, g0.x); FMA_MIX_HI(acc[1], q.x, g0.x);
        FMA_MIX_LO(acc[2], q.x, g0.y); FMA_MIX_HI(acc[3], q.x, g0.y);
        FMA_MIX_LO(acc[4], q.x, g0.z); FMA_MIX_HI(acc[5], q.x, g0.z);
        FMA_MIX_LO(acc[6], q.x, g0.w); FMA_MIX_HI(acc[7], q.x, g0.w);
        FMA_MIX_LO(acc[0], q.y, g1.x); FMA_MIX_HI(acc[1], q.y, g1.x);
        FMA_MIX_LO(acc[2], q.y, g1.y); FMA_MIX_HI(acc[3], q.y, g1.y);
        FMA_MIX_LO(acc[4], q.y, g1.z); FMA_MIX_HI(acc[5], q.y, g1.z);
        FMA_MIX_LO(acc[6], q.y, g1.w); FMA_MIX_HI(acc[7], q.y, g1.w);
        FMA_MIX_LO(acc[0], q.z, g2.x); FMA_MIX_HI(acc[1], q.z, g2.x);
        FMA_MIX_LO(acc[2], q.z, g2.y); FMA_MIX_HI(acc[3], q.z, g2.y);
        FMA_MIX_LO(acc[4], q.z, g2.z); FMA_MIX_HI(acc[5], q.z, g2.z);
        FMA_MIX_LO(acc[6], q.z, g2.w); FMA_MIX_HI(acc[7], q.z, g2.w);
        FMA_MIX_LO(acc[0], q.w, g3.x); FMA_MIX_HI(acc[1], q.w, g3.x);
        FMA_MIX_LO(acc[2], q.w, g3.y); FMA_MIX_HI(acc[3], q.w, g3.y);
        FMA_MIX_LO(acc[4], q.w, g3.z); FMA_MIX_HI(acc[5], q.w, g3.z);
        FMA_MIX_LO(acc[6], q.w, g3.w); FMA_MIX_HI(acc[7], q.w, g3.w);
    }

    float xn[8];
    if (k > 1) {
        const uint4 old = *(const uint4*)((const char*)Xown + ((size_t)v*1024 + loff));
        xn[0] = fmaf(2.f, acc[0], -h2f_lo(old.x));
        xn[1] = fmaf(2.f, acc[1], -h2f_hi(old.x));
        xn[2] = fmaf(2.f, acc[2], -h2f_lo(old.y));
        xn[3] = fmaf(2.f, acc[3], -h2f_hi(old.y));
        xn[4] = fmaf(2.f, acc[4], -h2f_lo(old.z));
        xn[5] = fmaf(2.f, acc[5], -h2f_hi(old.z));
        xn[6] = fmaf(2.f, acc[6], -h2f_lo(old.w));
        xn[7] = fmaf(2.f, acc[7], -h2f_hi(old.w));
    } else {
#pragma unroll
        for (int j = 0; j < 8; ++j) xn[j] = acc[j];
    }

    uint4 hp;
    { __half2 h0 = __floats2half2_rn(xn[0], xn[1]); hp.x = *(const unsigned*)&h0;
      __half2 h1 = __floats2half2_rn(xn[2], xn[3]); hp.y = *(const unsigned*)&h1;
      __half2 h2 = __floats2half2_rn(xn[4], xn[5]); hp.z = *(const unsigned*)&h2;
      __half2 h3 = __floats2half2_rn(xn[6], xn[7]); hp.w = *(const unsigned*)&h3; }
    *(uint4*)((char*)Xown + ((size_t)v*1024 + loff)) = hp;

    uint4 bp;
    bp.x = (unsigned)f2bf(xn[0]) | ((unsigned)f2bf(xn[1]) << 16);
    bp.y = (unsigned)f2bf(xn[2]) | ((unsigned)f2bf(xn[3]) << 16);
    bp.z = (unsigned)f2bf(xn[4]) | ((unsigned)f2bf(xn[5]) << 16);
    bp.w = (unsigned)f2bf(xn[6]) | ((unsigned)f2bf(xn[7]) << 16);
    *(uint4*)((char*)stk16 + (((size_t)k*V1_ + v)*1024 + loff)) = bp;
}

// ---------- W prep (conv): Wb[fin][g][f][kk] = bf16(W[f][fin*25+g*8+kk]), 0-padded ----------
template<int FIN, int F>
__global__ __launch_bounds__(256) void k_wprep(const float* __restrict__ W,
                                               unsigned short* __restrict__ Wb) {
    int idx = blockIdx.x*256 + threadIdx.x;
    int kk  = idx & 7;
    int f   = (idx >> 3) % F;
    int g   = (idx >> 3) / F % 4;
    int fin = idx / (8*F*4);
    int k = g*8 + kk;
    Wb[idx] = (k < K_) ? f2bf(W[(size_t)f*(FIN*K_) + fin*K_ + k]) : 0;
}

// ---------- W prep (fc1): f32 -> bf16 flat copy ----------
__global__ __launch_bounds__(256) void k_wprep_fc(const float* __restrict__ W,
                                                  unsigned short* __restrict__ Wb) {
    int idx = (blockIdx.x*256 + threadIdx.x)*4;
    float4 w = *(const float4*)&W[idx];
    ushort4 o;
    o.x = f2bf(w.x); o.y = f2bf(w.y); o.z = f2bf(w.z); o.w = f2bf(w.w);
    *(ushort4*)&Wb[idx] = o;
}

// ---------- layer-1 MFMA GEMM (stk16 [k][v][c]) + relu + pool -> X0T2[(f*64+b)][v2] ----------
__global__ __launch_bounds__(256) void k_gemm1b(const unsigned short* __restrict__ stk16,
                                                const unsigned short* __restrict__ Wb,
                                                const float* __restrict__ bias,
                                                float* __restrict__ X0T2) {
    const int t = threadIdx.x, lane = t & 63, wave = t >> 6;
    const int v2 = blockIdx.x*4 + wave;
    const int m = lane & 15, g = lane >> 4;
    int kbase[8];
#pragma unroll
    for (int j = 0; j < 8; ++j) {
        int kq = g*8 + j; if (kq > 24) kq = 24;
        kbase[j] = kq * (V1_*C1_);
    }
    float bv[2] = { bias[m], bias[16+m] };
    f32x4 pool[4][2];

    for (int vv = 0; vv < 4; ++vv) {
        const int v = v2*4 + vv;
        f32x4 acc[4][2];
#pragma unroll
        for (int mt = 0; mt < 4; ++mt)
#pragma unroll
            for (int ft = 0; ft < 2; ++ft) acc[mt][ft] = (f32x4){0.f,0.f,0.f,0.f};

        for (int fin = 0; fin < DF_; ++fin) {
            const int cbase = v*C1_ + fin*64 + m;
            const bf16x8 bw0 = *(const bf16x8*)&Wb[((fin*4+g)*F1_ + m)*8];
            const bf16x8 bw1 = *(const bf16x8*)&Wb[((fin*4+g)*F1_ + 16 + m)*8];
#pragma unroll
            for (int mt = 0; mt < 4; ++mt) {
                unsigned short au[8];
#pragma unroll
                for (int j = 0; j < 8; ++j)
                    au[j] = stk16[(size_t)(kbase[j] + cbase + mt*16)];
                bf16x8 a;
                __builtin_memcpy(&a, au, 16);
                acc[mt][0] = __builtin_amdgcn_mfma_f32_16x16x32_bf16(a, bw0, acc[mt][0], 0,0,0);
                acc[mt][1] = __builtin_amdgcn_mfma_f32_16x16x32_bf16(a, bw1, acc[mt][1], 0,0,0);
            }
        }
#pragma unroll
        for (int mt = 0; mt < 4; ++mt)
#pragma unroll
            for (int ft = 0; ft < 2; ++ft) {
                if (vv == 0) pool[mt][ft] = acc[mt][ft];
                else {
#pragma unroll
                    for (int j = 0; j < 4; ++j)
                        pool[mt][ft][j] = fmaxf(pool[mt][ft][j], acc[mt][ft][j]);
                }
            }
    }

#pragma unroll
    for (int mt = 0; mt < 4; ++mt)
#pragma unroll
        for (int ft = 0; ft < 2; ++ft)
#pragma unroll
            for (int j = 0; j < 4; ++j) {
                float mx = fmaxf(pool[mt][ft][j] + bv[ft], 0.f);
                int b = mt*16 + g*4 + j;
                int f = ft*16 + m;
                X0T2[(size_t)(f*64+b)*V2_ + v2] = mx;
            }
}

// ---------- layer-2 Chebyshev: 4 cols/block, f16x4 LDS ping-pong ----------
template<int V, int THREADS, int MINW>
__global__ __launch_bounds__(THREADS, MINW) void k_cheb2(
        const float* __restrict__ X0T,
        const int* __restrict__ offs,
        const unsigned* __restrict__ ep,
        unsigned* __restrict__ stk) {
    constexpr int RPT = V / THREADS;     // 2
    __shared__ uint2 buf[2*V];
    const int c0 = blockIdx.x*4;
    const int t = threadIdx.x;
    int e0r[RPT], e1r[RPT];
    unsigned tlo[RPT][4];
    unsigned* __restrict__ pl[4];
#pragma unroll
    for (int j = 0; j < 4; ++j) pl[j] = stk + (size_t)(c0+j)*NP_*V;

#pragma unroll
    for (int r = 0; r < RPT; ++r) {
        const int v = r*THREADS + t;
        e0r[r] = offs[v]; e1r[r] = offs[v+1];
        float xj[4];
#pragma unroll
        for (int j = 0; j < 4; ++j) {
            xj[j] = X0T[(size_t)(c0+j)*V + v];
            tlo[r][j] = f2bf(xj[j]);
        }
        __half2 ha = __floats2half2_rn(xj[0], xj[1]);
        __half2 hb = __floats2half2_rn(xj[2], xj[3]);
        buf[v] = make_uint2(*(const unsigned*)&ha, *(const unsigned*)&hb);
    }
    __syncthreads();

    auto step = [&](const uint2* __restrict__ src, uint2* __restrict__ dst,
                    bool first, bool last, int plane) {
#pragma unroll
        for (int r = 0; r < RPT; ++r) {
            const int v = r*THREADS + t;
            float acc[4][4];
#pragma unroll
            for (int j = 0; j < 4; ++j)
#pragma unroll
                for (int i = 0; i < 4; ++i) acc[j][i] = 0.f;
            const int ee0 = e0r[r], ee1 = e1r[r];
            uint4 q = *(const uint4*)&ep[ee0];
            for (int e = ee0; e < ee1; e += 4) {
                const uint4 qn = *(const uint4*)&ep[e + 4];
                const uint2 g0 = *(const uint2*)((const char*)src + (q.x & 0xFFFFu));
                const uint2 g1 = *(const uint2*)((const char*)src + (q.y & 0xFFFFu));
                const uint2 g2 = *(const uint2*)((const char*)src + (q.z & 0xFFFFu));
                const uint2 g3 = *(const uint2*)((const char*)src + (q.w & 0xFFFFu));
                FMA_MIX_LO(acc[0][0], q.x, g0.x); FMA_MIX_HI(acc[1][0], q.x, g0.x);
                FMA_MIX_LO(acc[2][0], q.x, g0.y); FMA_MIX_HI(acc[3][0], q.x, g0.y);
                FMA_MIX_LO(acc[0][1], q.y, g1.x); FMA_MIX_HI(acc[1][1], q.y, g1.x);
                FMA_MIX_LO(acc[2][1], q.y, g1.y); FMA_MIX_HI(acc[3][1], q.y, g1.y);
                FMA_MIX_LO(acc[0][2], q.z, g2.x); FMA_MIX_HI(acc[1][2], q.z, g2.x);
                FMA_MIX_LO(acc[2][2], q.z, g2.y); FMA_MIX_HI(acc[3][2], q.z, g2.y);
                FMA_MIX_LO(acc[0][3], q.w, g3.x); FMA_MIX_HI(acc[1][3], q.w, g3.x);
                FMA_MIX_LO(acc[2][3], q.w, g3.y); FMA_MIX_HI(acc[3][3], q.w, g3.y);
                q = qn;
            }
            float gs[4];
#pragma unroll
            for (int j = 0; j < 4; ++j)
                gs[j] = (acc[j][0]+acc[j][1])+(acc[j][2]+acc[j][3]);
            float xn[4];
            if (first) {
#pragma unroll
                for (int j = 0; j < 4; ++j) xn[j] = gs[j];
            } else {
                const uint2 old = dst[v];
                xn[0] = fmaf(2.f, gs[0], -h2f_lo(old.x));
                xn[1] = fmaf(2.f, gs[1], -h2f_hi(old.x));
                xn[2] = fmaf(2.f, gs[2], -h2f_lo(old.y));
                xn[3] = fmaf(2.f, gs[3], -h2f_hi(old.y));
            }
            if (!last) {
                __half2 ha = __floats2half2_rn(xn[0], xn[1]);
                __half2 hb = __floats2half2_rn(xn[2], xn[3]);
                dst[v] = make_uint2(*(const unsigned*)&ha, *(const unsigned*)&hb);
            }
            unsigned h[4];
#pragma unroll
            for (int j = 0; j < 4; ++j) h[j] = f2bf(xn[j]);
            if (plane < 0) {
#pragma unroll
                for (int j = 0; j < 4; ++j) tlo[r][j] = h[j];
            } else {
#pragma unroll
                for (int j = 0; j < 4; ++j)
                    pl[j][(size_t)plane*V + v] = tlo[r][j] | (h[j] << 16);
            }
        }
        __syncthreads();
    };

    step(buf, buf + V, true, false, 0);
    for (int k = 2; k < 24; k += 2) {
        step(buf + V, buf, false, false, -1);
        step(buf, buf + V, false, false, (k + 1) >> 1);
    }
    step(buf + V, buf, false, true, -1);

#pragma unroll
    for (int r = 0; r < RPT; ++r) {
        const int v = r*THREADS + t;
#pragma unroll
        for (int j = 0; j < 4; ++j)
            pl[j][(size_t)12*V + v] = tlo[r][j];
    }
}

// ---------- layer-2 MFMA GEMM + relu + pool -> ABF[b][v2*64+f] bf16 ----------
__global__ __launch_bounds__(256) void k_gemm2(const unsigned* __restrict__ STK,
                                               const unsigned short* __restrict__ Wb,
                                               const float* __restrict__ bias,
                                               unsigned short* __restrict__ ABF) {
    const int t = threadIdx.x, lane = t & 63, wave = t >> 6;
    const int b = blockIdx.x;
    const int v0 = blockIdx.y*128 + wave*32;
    const int m = lane & 15, g = lane >> 4;
    int offp[4];
#pragma unroll
    for (int p = 0; p < 4; ++p) {
        int pl = 4*g + p; if (pl > 12) pl = 12;
        offp[p] = pl*V2_ + v0 + m;
    }

    f32x4 acc[2][4];
#pragma unroll
    for (int mt = 0; mt < 2; ++mt)
#pragma unroll
        for (int ft = 0; ft < 4; ++ft) acc[mt][ft] = (f32x4){0.f,0.f,0.f,0.f};

#pragma unroll 4
    for (int fin = 0; fin < F1_; ++fin) {
        const unsigned* sp = STK + (size_t)(fin*64 + b)*(NP_*V2_);
        unsigned ua[4], ub[4];
#pragma unroll
        for (int p = 0; p < 4; ++p) { ua[p] = sp[offp[p]]; ub[p] = sp[offp[p] + 16]; }
        bf16x8 a0, a1;
        __builtin_memcpy(&a0, ua, 16);
        __builtin_memcpy(&a1, ub, 16);
#pragma unroll
        for (int ft = 0; ft < 4; ++ft) {
            const bf16x8 bw = *(const bf16x8*)&Wb[((fin*4+g)*F2_ + ft*16 + m)*8];
            acc[0][ft] = __builtin_amdgcn_mfma_f32_16x16x32_bf16(a0, bw, acc[0][ft], 0,0,0);
            acc[1][ft] = __builtin_amdgcn_mfma_f32_16x16x32_bf16(a1, bw, acc[1][ft], 0,0,0);
        }
    }
#pragma unroll
    for (int mt = 0; mt < 2; ++mt)
#pragma unroll
        for (int ft = 0; ft < 4; ++ft) {
            f32x4 a = acc[mt][ft];
            float mx = fmaxf(fmaxf(a[0],a[1]), fmaxf(a[2],a[3])) + bias[ft*16 + m];
            mx = fmaxf(mx, 0.f);
            int v2 = blockIdx.y*32 + wave*8 + mt*4 + g;
            ABF[(size_t)b*FCIN_ + v2*64 + ft*16 + m] = f2bf(mx);
        }
}

// ---------- FC1 MFMA: O[64][512] += A[64][16384]·W^T, bias pre-init ----------
__global__ __launch_bounds__(256) void k_fc1_init(const float* __restrict__ bias,
                                                  float* __restrict__ O) {
    int idx = blockIdx.x*256 + threadIdx.x;
    O[idx] = bias[idx & (FC1F_-1)];
}

__global__ __launch_bounds__(256) void k_fc1m(const unsigned short* __restrict__ ABF,
                                              const unsigned short* __restrict__ WBF,
                                              float* __restrict__ O) {
    const int t = threadIdx.x, lane = t & 63, wave = t >> 6;
    const int j0 = blockIdx.x*16;
    const int k0 = blockIdx.y*1024;
    const int m = lane & 15, g = lane >> 4;
    const int m0 = wave*16;
    f32x4 acc = (f32x4){0.f,0.f,0.f,0.f};
#pragma unroll 4
    for (int k = k0; k < k0+1024; k += 32) {
        const bf16x8 a = *(const bf16x8*)&ABF[(size_t)(m0+m)*FCIN_ + k + g*8];
        const bf16x8 w = *(const bf16x8*)&WBF[(size_t)(j0+m)*FCIN_ + k + g*8];
        acc = __builtin_amdgcn_mfma_f32_16x16x32_bf16(a, w, acc, 0,0,0);
    }
    // C/D: col = lane&15 (j), row = (lane>>4)*4 + reg (b within tile)
#pragma unroll
    for (int r = 0; r < 4; ++r)
        atomicAdd(&O[(size_t)(m0 + g*4 + r)*FC1F_ + j0 + m], acc[r]);
}

// ---------- FC2 (relu on FC1 output applied here) ----------
__global__ void k_fc2(const float* __restrict__ O1, const float* __restrict__ W2,
                      const float* __restrict__ b2, float* __restrict__ out) {
    int c = blockIdx.x;
    int b = threadIdx.x;
    float s = b2[c];
    for (int j = 0; j < FC1F_; ++j)
        s = fmaf(fmaxf(O1[b*FC1F_ + j], 0.f), W2[c*FC1F_ + j], s);
    out[b*FC2F_ + c] = s;
}

extern "C" void kernel_launch(void* const* d_in, const int* in_sizes, int n_in,
                              void* d_out, int out_size, void* d_ws, size_t ws_size,
                              hipStream_t stream) {
    const float* x   = (const float*)d_in[0];
    const int*   l1r = (const int*)d_in[1];
    const int*   l1c = (const int*)d_in[2];
    const float* l1v = (const float*)d_in[3];
    const int*   l2r = (const int*)d_in[4];
    const int*   l2c = (const int*)d_in[5];
    const float* l2v = (const float*)d_in[6];
    const float* w1  = (const float*)d_in[7];
    const float* b1  = (const float*)d_in[8];
    const float* w2  = (const float*)d_in[9];
    const float* b2  = (const float*)d_in[10];
    const float* fw1 = (const float*)d_in[11];
    const float* fb1 = (const float*)d_in[12];
    const float* fw2 = (const float*)d_in[13];
    const float* fb2 = (const float*)d_in[14];
    float* out = (float*)d_out;

    char* wsp = (char*)d_ws;
    size_t off = 0;
    auto alloc = [&](size_t bytes) -> void* {
        void* p = wsp + off;
        off += (bytes + 255) & ~size_t(255);
        return p;
    };
    // shared big buffer: stk16 (layer-1) then STACK (layer-2), stream-ordered reuse.
    void*     STKU  = alloc((size_t)C2_*NP_*V2_*4);                     // 109 MB
    unsigned short* stk16 = (unsigned short*)STKU;
    unsigned*       STACK = (unsigned*)STKU;
    unsigned short* XB0   = (unsigned short*)alloc((size_t)V1_*C1_*2);  // 4 MB
    unsigned short* XB1   = (unsigned short*)alloc((size_t)V1_*C1_*2);  // 4 MB
    float*    X0T2  = (float*)alloc((size_t)C2_*V2_*4);                 // 8 MB
    unsigned short* ABF = (unsigned short*)alloc((size_t)B_*FCIN_*2);   // 2 MB
    unsigned short* WBF = (unsigned short*)alloc((size_t)FC1F_*FCIN_*2);// 16.7 MB
    float*    FC1O  = (float*)alloc((size_t)B_*FC1F_*4);
    unsigned short* WB1 = (unsigned short*)alloc((size_t)DF_*4*F1_*8*2);
    unsigned short* WB2 = (unsigned short*)alloc((size_t)F1_*4*F2_*8*2);
    int*      cnt1  = (int*)alloc(V1_*4);
    int*      offs1 = (int*)alloc((V1_+1)*4);
    int*      cur1  = (int*)alloc(V1_*4);
    unsigned* ep1   = (unsigned*)alloc((size_t)(E1_ + 4*V1_ + 8)*4);
    int*      cnt2  = (int*)alloc(V2_*4);
    int*      offs2 = (int*)alloc((V2_+1)*4);
    int*      cur2  = (int*)alloc(V2_*4);
    unsigned* ep2   = (unsigned*)alloc((size_t)(E2_ + 4*V2_ + 8)*4);

    // --- CSR build both layers + W prep ---
    hipMemsetAsync(cnt1, 0, V1_*4, stream);
    hipMemsetAsync(ep1, 0, (size_t)(E1_ + 4*V1_ + 8)*4, stream);
    hipMemsetAsync(cnt2, 0, V2_*4, stream);
    hipMemsetAsync(ep2, 0, (size_t)(E2_ + 4*V2_ + 8)*4, stream);
    hipLaunchKernelGGL(k_count,   dim3(E1_/256), dim3(256), 0, stream, l1r, E1_, cnt1);
    hipLaunchKernelGGL(k_scan,    dim3(1),       dim3(256), 0, stream, cnt1, V1_, offs1, cur1);
    hipLaunchKernelGGL(k_scatter, dim3(E1_/256), dim3(256), 0, stream, l1r, l1c, l1v, E1_, 0, cur1, ep1);
    hipLaunchKernelGGL(k_count,   dim3(E2_/256), dim3(256), 0, stream, l2r, E2_, cnt2);
    hipLaunchKernelGGL(k_scan,    dim3(1),       dim3(256), 0, stream, cnt2, V2_, offs2, cur2);
    hipLaunchKernelGGL(k_scatter, dim3(E2_/256), dim3(256), 0, stream, l2r, l2c, l2v, E2_, 3, cur2, ep2);
    hipLaunchKernelGGL((k_wprep<DF_,F1_>), dim3(DF_*4*F1_*8/256), dim3(256), 0, stream, w1, WB1);
    hipLaunchKernelGGL((k_wprep<F1_,F2_>), dim3(F1_*4*F2_*8/256), dim3(256), 0, stream, w2, WB2);
    hipLaunchKernelGGL(k_wprep_fc, dim3(FC1F_*FCIN_/1024), dim3(256), 0, stream, fw1, WBF);

    // --- layer 1: dual-cheb, one launch per k-step ---
    hipLaunchKernelGGL(k_transpose_rm, dim3(V1_/16), dim3(256), 0, stream,
                       x, (unsigned*)XB0, (unsigned*)stk16);
    for (int k = 1; k <= 24; ++k) {
        unsigned short* src = (k & 1) ? XB0 : XB1;
        unsigned short* own = (k & 1) ? XB1 : XB0;
        hipLaunchKernelGGL(k_dcheb1, dim3(V1_/8), dim3(512), 0, stream,
                           k, src, own, stk16, offs1, ep1);
    }
    hipLaunchKernelGGL(k_gemm1b, dim3(V2_/4), dim3(256), 0, stream, stk16, WB1, b1, X0T2);

    // --- layer 2 ---
    hipLaunchKernelGGL((k_cheb2<V2_,512,4>), dim3(C2_/4), dim3(512), 0, stream,
                       X0T2, offs2, ep2, STACK);
    hipLaunchKernelGGL(k_gemm2, dim3(64, 8), dim3(256), 0, stream, STACK, WB2, b2, ABF);

    // --- FC ---
    hipLaunchKernelGGL(k_fc1_init, dim3(B_*FC1F_/256), dim3(256), 0, stream, fb1, FC1O);
    hipLaunchKernelGGL(k_fc1m, dim3(32, 16), dim3(256), 0, stream, ABF, WBF, FC1O);
    hipLaunchKernelGGL(k_fc2, dim3(FC2F_), dim3(B_), 0, stream, FC1O, fw2, fb2, out);
}